// Round 9
// baseline (220.448 us; speedup 1.0000x reference)
//
#include <hip/hip_runtime.h>
#include <hip/hip_bf16.h>
#include <hip/hip_fp16.h>
#include <math.h>

typedef __hip_bfloat16 bf16;
typedef unsigned int u32;
typedef __attribute__((ext_vector_type(8))) short short8;
typedef __attribute__((ext_vector_type(4))) float float4v;

#define T_   4
#define C_   64
#define H_   96
#define W_   96
#define CI_  16
#define HW_  9216
#define NC_  441
#define K_   100
#define NTILE 576
#define HSEL 0x07060302u
#define LSEL 0x05040100u

__device__ __forceinline__ float ldbf(const void* p, int i) { return __bfloat162float(((const bf16*)p)[i]); }
__device__ __forceinline__ float ldf (const void* p, int i) { return ((const float*)p)[i]; }

__device__ __forceinline__ unsigned short f2bf(float x) {
    union { float f; u32 u; } a; a.f = x;
    u32 r = a.u + 0x7FFF + ((a.u >> 16) & 1);
    return (unsigned short)(r >> 16);
}
__device__ __forceinline__ float bf2f(unsigned short s) {
    union { u32 u; float f; } a; a.u = ((u32)s) << 16;
    return a.f;
}
__device__ __forceinline__ u32 packbf(float x) {
    unsigned short h = f2bf(x);
    unsigned short l = f2bf(x - bf2f(h));
    return ((u32)h << 16) | (u32)l;
}
__device__ __forceinline__ u32 okey(float f) {
    u32 u = __float_as_uint(f);
    return u ^ ((u & 0x80000000u) ? 0xFFFFFFFFu : 0x80000000u);
}
__device__ __forceinline__ float unokey(u32 k) {
    u32 u = (k & 0x80000000u) ? (k ^ 0x80000000u) : ~k;
    return __uint_as_float(u);
}
__device__ __forceinline__ int cntdim(int x) {
    int c = 0;
#pragma unroll
    for (int pp = 0; pp < 7; pp++) {
        int q = x - pp;
        c += (q >= 0 && q <= 92 && ((q & 3) == 0)) ? 1 : 0;
    }
    if (x == 95) c += 3;
    return c;
}

// per-block dtype vote (fp32 low-mantissa words decode to "insane" bf16 exponents)
__device__ __forceinline__ int detect_flag(const void* vid, int tid, int* sflag) {
    if (tid < 64) {
        unsigned short w = ((const unsigned short*)vid)[tid * 2];
        int e = (w >> 7) & 0xFF;
        int sane = ((e >= 100 && e <= 140) || ((w & 0x7FFF) == 0)) ? 1 : 0;
#pragma unroll
        for (int off = 1; off < 64; off <<= 1) sane += __shfl_xor(sane, off);
        if (tid == 0) *sflag = (sane >= 48) ? 1 : 0;
    }
    __syncthreads();
    return *sflag;
}

// ---------------- conv1x1 x3 + format conversion + ACC zero + queue reset ----------------
__global__ __launch_bounds__(256) void conv3_k(const void* vid, const void* gw, const void* gb,
                                               const void* tw, const void* tb, const void* pw,
                                               const void* pb,
                                               u32* __restrict__ B1p, __half* __restrict__ B2h,
                                               u32* __restrict__ B3p, float* __restrict__ ACCb,
                                               int* __restrict__ cnt)
{
    __shared__ float w[3120];
    __shared__ int sflag;
    int tid = threadIdx.x;
    if (blockIdx.x == 0 && tid == 0) *cnt = 0;
    int isbf = detect_flag(vid, tid, &sflag);
    if (isbf) {
        for (int i = tid; i < 3120; i += 256) {
            float v;
            if (i < 1024) v = ldbf(gw, i);
            else if (i < 2048) v = ldbf(tw, i - 1024);
            else if (i < 3072) v = ldbf(pw, i - 2048);
            else if (i < 3088) v = ldbf(gb, i - 3072);
            else if (i < 3104) v = ldbf(tb, i - 3088);
            else v = ldbf(pb, i - 3104);
            w[i] = v;
        }
    } else {
        for (int i = tid; i < 3120; i += 256) {
            float v;
            if (i < 1024) v = ldf(gw, i);
            else if (i < 2048) v = ldf(tw, i - 1024);
            else if (i < 3072) v = ldf(pw, i - 2048);
            else if (i < 3088) v = ldf(gb, i - 3072);
            else if (i < 3104) v = ldf(tb, i - 3088);
            else v = ldf(pb, i - 3104);
            w[i] = v;
        }
    }
    __syncthreads();

    {
        float4v z = {0.f, 0.f, 0.f, 0.f};
        *(float4v*)(ACCb + (blockIdx.x * 256 + tid) * 4) = z;
    }

    int lane = tid & 63, og = tid >> 6;
    int g0 = blockIdx.x * 64 + lane;          // 576*64 = 36864 exactly
    int t = g0 / HW_, pix = g0 - t * HW_;

    float a1[4], a2[4], a3[4];
#pragma unroll
    for (int k = 0; k < 4; k++) {
        a1[k] = w[3072 + og * 4 + k];
        a2[k] = w[3088 + og * 4 + k];
        a3[k] = w[3104 + og * 4 + k];
    }
    int base = t * C_ * HW_ + pix;
#pragma unroll 16
    for (int c = 0; c < C_; c++) {
        float v = isbf ? ldbf(vid, base + c * HW_) : ldf(vid, base + c * HW_);
#pragma unroll
        for (int k = 0; k < 4; k++) {
            a1[k] += v * w[(og * 4 + k) * 64 + c];
            a2[k] += v * w[1024 + (og * 4 + k) * 64 + c];
            a3[k] += v * w[2048 + (og * 4 + k) * 64 + c];
        }
    }
    int ob = g0 * 16 + og * 4;
    uint4 p1, p3;
    p1.x = packbf(a1[0]); p1.y = packbf(a1[1]); p1.z = packbf(a1[2]); p1.w = packbf(a1[3]);
    p3.x = packbf(a3[0]); p3.y = packbf(a3[1]); p3.z = packbf(a3[2]); p3.w = packbf(a3[3]);
    *(uint4*)(B1p + ob) = p1;
    *(uint4*)(B3p + ob) = p3;
    __half2 h01 = __floats2half2_rn(a2[0], a2[1]);
    __half2 h23 = __floats2half2_rn(a2[2], a2[3]);
    uint2 p2;
    p2.x = *(u32*)&h01; p2.y = *(u32*)&h23;
    *(uint2*)(B2h + ob) = p2;
}

// ---------------- fused attention: PERSISTENT blocks + atomic tile queue ----------------
// 512 blocks (2/CU even), tiles 0..575 pulled from global counter (straggler fix).
// One tile = 2x2 queries; 32x32 virtual window, two-phase bf16 h/l score GEMM,
// per-wave radix-256 exact top-100 (clip-remap folded into key gather; ties are
// bitwise dups = interchangeable), wave-private softmax + f16 PV, channel-major atomics.
__global__ __launch_bounds__(256, 2) void attn_k(const u32* __restrict__ B1p,
                                                 const __half* __restrict__ B2h,
                                                 const u32* __restrict__ B3p,
                                                 float* __restrict__ ACCb,
                                                 int* __restrict__ cnt)
{
    __shared__ __align__(16) char SM[47264];
    short*   Win  = (short*)SM;
    float*   Sc   = (float*)(SM + 32768);
    float*   Cb   = (float*)(SM + 39824);
    int*     hist = (int*)(SM + 39824);
    float*   yiw  = (float*)(SM + 43920);
    int*     pab  = (int*)(SM + 45520);
    int*     ctl  = (int*)(SM + 47120);
    int*     tctl = (int*)(SM + 47248);
    __half2* Wp   = (__half2*)SM;

    int tid = threadIdx.x;
    int lane = tid & 63, wv = tid >> 6;
    int nn = lane & 15, qsel = nn >> 3, pjn = nn & 7;
    int koff = (lane >> 4) * 8;

    for (;;) {
        if (tid == 0) tctl[0] = atomicAdd(cnt, 1);
        __syncthreads();
        int tileid = tctl[0];
        if (tileid >= NTILE) break;
        int t = tileid / 144, tile = tileid - t * 144;
        int qy = tile / 12, qx = tile - qy * 12;
        int qi = qy * 8, qj = qx * 8;

        const u32*    B1t = B1p + t * HW_ * 16;
        const __half* B2t = B2h + t * HW_ * 16;
        const u32*    B3t = B3p + t * HW_ * 16;

        // ---- stage h-plane: 32x32 window ----
        for (int pos = tid; pos < 1024; pos += 256) {
            int row = pos >> 5, col = pos & 31;
            int vr = min(max(qi - 10 + row, 0), 95);
            int vc = min(max(qj - 10 + col, 0), 95);
            const u32* src = B3t + (vr * 96 + vc) * 16;
            uint4 U0 = *(const uint4*)src,       U1 = *(const uint4*)(src + 4);
            uint4 U2 = *(const uint4*)(src + 8), U3 = *(const uint4*)(src + 12);
            uint4 A, B;
            A.x = __builtin_amdgcn_perm(U0.y, U0.x, HSEL);
            A.y = __builtin_amdgcn_perm(U0.w, U0.z, HSEL);
            A.z = __builtin_amdgcn_perm(U1.y, U1.x, HSEL);
            A.w = __builtin_amdgcn_perm(U1.w, U1.z, HSEL);
            B.x = __builtin_amdgcn_perm(U2.y, U2.x, HSEL);
            B.y = __builtin_amdgcn_perm(U2.w, U2.z, HSEL);
            B.z = __builtin_amdgcn_perm(U3.y, U3.x, HSEL);
            B.w = __builtin_amdgcn_perm(U3.w, U3.z, HSEL);
            *(uint4*)(Win + pos * 16)     = A;
            *(uint4*)(Win + pos * 16 + 8) = B;
        }
        __syncthreads();

        // ---- score phase A: Ah*Bh + Ah*Bl, query rows ri = 0,1 ----
#pragma unroll 1
        for (int ri = 0; ri < 2; ri++) {
            short8 Bh[4], Bl[4];
            int qiq = qi + 4 * ri, qjq = qj + 4 * qsel;
#pragma unroll
            for (int s = 0; s < 4; s++) {
                int kk0 = s * 32 + koff;
                int pi = kk0 >> 4, c0 = kk0 & 15;
                uint4 U0 = {0, 0, 0, 0}, U1 = {0, 0, 0, 0};
                if (pjn < 7 && pi < 7) {
                    const u32* src = B1t + (min(qiq + pi, 95) * 96 + min(qjq + pjn, 95)) * 16 + c0;
                    U0 = *(const uint4*)src;
                    U1 = *(const uint4*)(src + 4);
                }
                union { uint4 u; short8 s8; } hc, lc;
                hc.u.x = __builtin_amdgcn_perm(U0.y, U0.x, HSEL);
                hc.u.y = __builtin_amdgcn_perm(U0.w, U0.z, HSEL);
                hc.u.z = __builtin_amdgcn_perm(U1.y, U1.x, HSEL);
                hc.u.w = __builtin_amdgcn_perm(U1.w, U1.z, HSEL);
                lc.u.x = __builtin_amdgcn_perm(U0.y, U0.x, LSEL);
                lc.u.y = __builtin_amdgcn_perm(U0.w, U0.z, LSEL);
                lc.u.z = __builtin_amdgcn_perm(U1.y, U1.x, LSEL);
                lc.u.w = __builtin_amdgcn_perm(U1.w, U1.z, LSEL);
                Bh[s] = hc.s8; Bl[s] = lc.s8;
            }
            float* Cw = Cb + wv * 256;
            for (int r = wv; r < 21; r += 4) {
                float psum = 0.f;
                int v = (lane >= 21) ? 1 : 0;
                int b = lane - v * 21;
#pragma unroll
                for (int st = 0; st < 2; st++) {
                    float4v acc = {0.f, 0.f, 0.f, 0.f};
#pragma unroll
                    for (int s = 0; s < 4; s++) {
                        int arow = 4 * ri + r + 2 * s + (lane >> 5);
                        int aoff = (arow * 32 + st * 16 + nn) * 16 + ((lane >> 4) & 1) * 8;
                        short8 A = *(const short8*)(Win + aoff);
                        acc = __builtin_amdgcn_mfma_f32_16x16x32_bf16(A, Bh[s], acc, 0, 0, 0);
                        acc = __builtin_amdgcn_mfma_f32_16x16x32_bf16(A, Bl[s], acc, 0, 0, 0);
                    }
                    *(float4v*)(Cw + nn * 16 + (lane >> 4) * 4) = acc;
                    if (lane < 42) {
#pragma unroll
                        for (int pj = 0; pj < 7; pj++) {
                            int sp = b + 4 * v + pj;
                            if ((sp >> 4) == st) psum += Cw[(8 * v + pj) * 16 + (sp & 15)];
                        }
                    }
                }
                if (lane < 42) Sc[(ri * 2 + v) * 441 + r * 21 + b] = psum;
            }
        }
        __syncthreads();

        // ---- stage l-plane (same packed source, L1-hot) ----
        for (int pos = tid; pos < 1024; pos += 256) {
            int row = pos >> 5, col = pos & 31;
            int vr = min(max(qi - 10 + row, 0), 95);
            int vc = min(max(qj - 10 + col, 0), 95);
            const u32* src = B3t + (vr * 96 + vc) * 16;
            uint4 U0 = *(const uint4*)src,       U1 = *(const uint4*)(src + 4);
            uint4 U2 = *(const uint4*)(src + 8), U3 = *(const uint4*)(src + 12);
            uint4 A, B;
            A.x = __builtin_amdgcn_perm(U0.y, U0.x, LSEL);
            A.y = __builtin_amdgcn_perm(U0.w, U0.z, LSEL);
            A.z = __builtin_amdgcn_perm(U1.y, U1.x, LSEL);
            A.w = __builtin_amdgcn_perm(U1.w, U1.z, LSEL);
            B.x = __builtin_amdgcn_perm(U2.y, U2.x, LSEL);
            B.y = __builtin_amdgcn_perm(U2.w, U2.z, LSEL);
            B.z = __builtin_amdgcn_perm(U3.y, U3.x, LSEL);
            B.w = __builtin_amdgcn_perm(U3.w, U3.z, LSEL);
            *(uint4*)(Win + pos * 16)     = A;
            *(uint4*)(Win + pos * 16 + 8) = B;
        }
        __syncthreads();

        // ---- score phase B: Sc += Al*Bh ----
#pragma unroll 1
        for (int ri = 0; ri < 2; ri++) {
            short8 Bh[4];
            int qiq = qi + 4 * ri, qjq = qj + 4 * qsel;
#pragma unroll
            for (int s = 0; s < 4; s++) {
                int kk0 = s * 32 + koff;
                int pi = kk0 >> 4, c0 = kk0 & 15;
                uint4 U0 = {0, 0, 0, 0}, U1 = {0, 0, 0, 0};
                if (pjn < 7 && pi < 7) {
                    const u32* src = B1t + (min(qiq + pi, 95) * 96 + min(qjq + pjn, 95)) * 16 + c0;
                    U0 = *(const uint4*)src;
                    U1 = *(const uint4*)(src + 4);
                }
                union { uint4 u; short8 s8; } hc;
                hc.u.x = __builtin_amdgcn_perm(U0.y, U0.x, HSEL);
                hc.u.y = __builtin_amdgcn_perm(U0.w, U0.z, HSEL);
                hc.u.z = __builtin_amdgcn_perm(U1.y, U1.x, HSEL);
                hc.u.w = __builtin_amdgcn_perm(U1.w, U1.z, HSEL);
                Bh[s] = hc.s8;
            }
            float* Cw = Cb + wv * 256;
            for (int r = wv; r < 21; r += 4) {
                float psum = 0.f;
                int v = (lane >= 21) ? 1 : 0;
                int b = lane - v * 21;
#pragma unroll
                for (int st = 0; st < 2; st++) {
                    float4v acc = {0.f, 0.f, 0.f, 0.f};
#pragma unroll
                    for (int s = 0; s < 4; s++) {
                        int arow = 4 * ri + r + 2 * s + (lane >> 5);
                        int aoff = (arow * 32 + st * 16 + nn) * 16 + ((lane >> 4) & 1) * 8;
                        short8 A = *(const short8*)(Win + aoff);
                        acc = __builtin_amdgcn_mfma_f32_16x16x32_bf16(A, Bh[s], acc, 0, 0, 0);
                    }
                    *(float4v*)(Cw + nn * 16 + (lane >> 4) * 4) = acc;
                    if (lane < 42) {
#pragma unroll
                        for (int pj = 0; pj < 7; pj++) {
                            int sp = b + 4 * v + pj;
                            if ((sp >> 4) == st) psum += Cw[(8 * v + pj) * 16 + (sp & 15)];
                        }
                    }
                }
                if (lane < 42) Sc[(ri * 2 + v) * 441 + r * 21 + b] += psum;
            }
        }
        __syncthreads();

        // ---- stage PV f16 plane + init hist/ctl (no fixup pass: remap at key gather) ----
        for (int pos = tid; pos < 992; pos += 256) {
            int row = pos >> 5, col = pos & 31;
            int vr = min(max(qi - 10 + row, 0), 95);
            int vc = min(max(qj - 10 + col, 0), 95);
            const __half* src = B2t + (vr * 96 + vc) * 16;
            *(int4*)(Wp + pos * 8)     = *(const int4*)src;
            *(int4*)(Wp + pos * 8 + 4) = *(const int4*)(src + 8);
        }
        hist[tid] = 0; hist[256 + tid] = 0; hist[512 + tid] = 0; hist[768 + tid] = 0;
        if (tid < 32) ctl[tid] = ((tid & 7) == 1) ? K_ : 0;
        __syncthreads();

        // ---- per-wave radix-256 exact top-100 (clip-remapped keys) ----
        int g = wv;
        int ri = g >> 1, ci = g & 1;
        int qiq = qi + 4 * ri, qjq = qj + 4 * ci;
        int alo = max(0, 10 - qiq), ahi = min(20, 105 - qiq);
        int blo = max(0, 10 - qjq), bhi = min(20, 105 - qjq);
        u32 kreg[7]; int ni = 0;
        u32 kmax = 0;
        for (int i = lane; i < NC_; i += 64) {
            int aa = i / 21, bb = i - aa * 21;
            int ae = min(max(aa, alo), ahi), be = min(max(bb, blo), bhi);
            u32 k = okey(Sc[g * 441 + ae * 21 + be]);
            kmax = max(kmax, k);
            kreg[ni++] = k;
        }
#pragma unroll
        for (int off = 1; off < 64; off <<= 1) kmax = max(kmax, (u32)__shfl_xor((int)kmax, off));

        for (int ps = 3; ps >= 0; ps--) {
            u32 pref = (u32)ctl[g * 8];
            if (!ctl[g * 8 + 3]) {
                for (int a = 0; a < ni; a++) {
                    u32 k = kreg[a];
                    if (ps == 3 || (k >> ((ps + 1) * 8)) == pref)
                        atomicAdd(&hist[g * 256 + ((k >> (ps * 8)) & 255)], 1);
                }
            }
            __syncthreads();
            if (!ctl[g * 8 + 3]) {
                int4 hv = *(int4*)(hist + g * 256 + lane * 4);
                int local = hv.x + hv.y + hv.z + hv.w;
                int s = local;
#pragma unroll
                for (int off = 1; off < 64; off <<= 1) {
                    int tt = __shfl_down(s, off);
                    if (lane + off < 64) s += tt;
                }
                int c4 = s - local;
                int c3 = c4 + hv.w, c2 = c3 + hv.z, c1 = c2 + hv.y, c0 = s;
                int need = ctl[g * 8 + 1];
                u32 pf = (u32)ctl[g * 8];
                int cums[5] = {c0, c1, c2, c3, c4};
                int hk[4] = {hv.x, hv.y, hv.z, hv.w};
#pragma unroll
                for (int k = 0; k < 4; k++) {
                    if (cums[k] >= need && cums[k + 1] < need) {
                        int newneed = need - cums[k + 1];
                        ctl[g * 8]     = (int)((pf << 8) | (u32)(lane * 4 + k));
                        ctl[g * 8 + 1] = newneed;
                        if (newneed == hk[k] || ps == 0) { ctl[g * 8 + 3] = 1; ctl[g * 8 + 2] = 8 * ps; }
                    }
                }
                int4 zz = {0, 0, 0, 0};
                *(int4*)(hist + g * 256 + lane * 4) = zz;
            }
            __syncthreads();
            if (ctl[3] && ctl[11] && ctl[19] && ctl[27]) break;
        }

        // ---- selection (wave-private; score reconstructed exactly via unokey) ----
        {
            u32 theta = (u32)ctl[g * 8];
            int shift = ctl[g * 8 + 2];
            int need  = ctl[g * 8 + 1];
            int base  = K_ - need;
            int a2 = 0;
            for (int i = lane; i < NC_; i += 64) {
                u32 k = kreg[a2++];
                u32 hp = k >> shift;
                int slot = -1;
                if (hp > theta) slot = atomicAdd(&ctl[g * 8 + 4], 1);
                else if (hp == theta) {
                    int j = atomicAdd(&ctl[g * 8 + 5], 1);
                    if (j < need) slot = base + j;
                }
                if (slot >= 0) {
                    int a = i / 21, b = i - a * 21;
                    int ae = min(max(a, alo), ahi), be = min(max(b, blo), bhi);
                    yiw[g * 100 + slot] = unokey(k);
                    pab[g * 100 + slot] = ((ae + 4 * ri) << 8) | (be + 4 * ci);
                }
            }
        }
        // ---- softmax (wave-private) ----
        {
            float m = unokey(kmax);
            float wa = expf((yiw[g * 100 + lane] - m) * 10.f);
            float wb2 = (lane < 36) ? expf((yiw[g * 100 + 64 + lane] - m) * 10.f) : 0.f;
            float ssum = wa + wb2;
#pragma unroll
            for (int off = 1; off < 64; off <<= 1) ssum += __shfl_xor(ssum, off);
            float inv = 1.f / ssum;
            yiw[g * 100 + lane] = wa * inv;
            if (lane < 36) yiw[g * 100 + 64 + lane] = wb2 * inv;
        }

        // ---- PV: wave owns its query; channel-major atomics ----
        if (lane < 49) {
            int pi = lane / 7, pj = lane - pi * 7;
            int rsel = lane & 1;
            __half2 z[8];
#pragma unroll
            for (int j = 0; j < 8; j++) z[j] = __float2half2_rn(0.f);
            for (int k = 0; k < K_; k++) {
                float y = yiw[g * 100 + k];
                int pp = pab[g * 100 + k];
                int row = (pp >> 8) + pi, col = (pp & 255) + pj;
                const __half2* cell = Wp + (row * 32 + col) * 8;
                int4 A0 = *(const int4*)(cell + rsel * 4);
                int4 A1 = *(const int4*)(cell + 4 - rsel * 4);
                const __half2* pa = (const __half2*)&A0;
                const __half2* pb2 = (const __half2*)&A1;
                __half2 yh = __float2half2_rn(y);
#pragma unroll
                for (int j = 0; j < 4; j++) {
                    z[j]     = __hfma2(pa[j],  yh, z[j]);
                    z[4 + j] = __hfma2(pb2[j], yh, z[4 + j]);
                }
            }
            int orow = min(qiq + pi, 95), ocol = min(qjq + pj, 95);
            float* dst = ACCb + t * CI_ * HW_ + orow * 96 + ocol;
            int c0 = rsel * 8, c1 = 8 - c0;
#pragma unroll
            for (int jh = 0; jh < 4; jh++) {
                atomicAdd(dst + (c0 + 2 * jh) * HW_,     __low2float(z[jh]));
                atomicAdd(dst + (c0 + 2 * jh + 1) * HW_, __high2float(z[jh]));
                atomicAdd(dst + (c1 + 2 * jh) * HW_,     __low2float(z[4 + jh]));
                atomicAdd(dst + (c1 + 2 * jh + 1) * HW_, __high2float(z[4 + jh]));
            }
        }
        __syncthreads();   // protect Win/Sc/ctl reuse next tile
    }
}

// ---------------- final: y = ACC/Z (Z analytic), conv1x1 + residual ----------------
__global__ __launch_bounds__(256) void out_k(const void* vid, const void* Ww, const void* Wb,
                                             const float* __restrict__ ACCb, void* out)
{
    __shared__ float w[1088];
    __shared__ int sflag;
    int tid = threadIdx.x;
    int isbf = detect_flag(vid, tid, &sflag);
    if (isbf) { for (int i = tid; i < 1088; i += 256) w[i] = (i < 1024) ? ldbf(Ww, i) : ldbf(Wb, i - 1024); }
    else      { for (int i = tid; i < 1088; i += 256) w[i] = (i < 1024) ? ldf (Ww, i) : ldf (Wb, i - 1024); }
    __syncthreads();

    int lane5 = tid & 31, oct = tid >> 5;
    int g0 = blockIdx.x * 32 + lane5;           // 1152*32 = 36864 exactly
    int t = g0 / HW_, pix = g0 - t * HW_;
    int pi = pix / 96, pj = pix - pi * 96;
    float invz = 1.f / (float)(cntdim(pi) * cntdim(pj));

    float y[CI_];
    int ab = t * CI_ * HW_ + pix;
#pragma unroll
    for (int ci = 0; ci < CI_; ci++) y[ci] = ACCb[ab + ci * HW_] * invz;

    int vb = t * C_ * HW_ + pix;
#pragma unroll
    for (int co = oct * 8; co < oct * 8 + 8; co++) {
        float s = w[1024 + co];
#pragma unroll
        for (int ci = 0; ci < CI_; ci++) s += w[co * 16 + ci] * y[ci];
        int idx = vb + co * HW_;
        float vv = isbf ? ldbf(vid, idx) : ldf(vid, idx);
        float r = vv + s;
        if (isbf) ((bf16*)out)[idx] = __float2bfloat16(r);
        else      ((float*)out)[idx] = r;
    }
}

extern "C" void kernel_launch(void* const* d_in, const int* in_sizes, int n_in,
                              void* d_out, int out_size, void* d_ws, size_t ws_size,
                              hipStream_t stream)
{
    // ws byte layout: B1p @0, B2h @2359296, B3p @3538944, ACC @5898240, cnt @8257536
    char* ws = (char*)d_ws;
    u32*    B1p  = (u32*)ws;
    __half* B2h  = (__half*)(ws + 2359296);
    u32*    B3p  = (u32*)(ws + 3538944);
    float*  ACCb = (float*)(ws + 5898240);
    int*    cnt  = (int*)(ws + 8257536);

    conv3_k<<<dim3(576), dim3(256), 0, stream>>>(d_in[0], d_in[1], d_in[2], d_in[3], d_in[4],
                                                 d_in[5], d_in[6], B1p, B2h, B3p, ACCb, cnt);
    attn_k<<<dim3(512), dim3(256), 0, stream>>>(B1p, B2h, B3p, ACCb, cnt);
    out_k<<<dim3(1152), dim3(256), 0, stream>>>(d_in[0], d_in[7], d_in[8], ACCb, d_out);
}

// Round 10
// 182.451 us; speedup vs baseline: 1.2083x; 1.2083x over previous
//
#include <hip/hip_runtime.h>
#include <hip/hip_bf16.h>
#include <hip/hip_fp16.h>
#include <math.h>

typedef __hip_bfloat16 bf16;
typedef unsigned int u32;
typedef __attribute__((ext_vector_type(8))) short short8;
typedef __attribute__((ext_vector_type(4))) float float4v;

#define T_   4
#define C_   64
#define H_   96
#define W_   96
#define CI_  16
#define HW_  9216
#define NC_  441
#define K_   100
#define HSEL 0x07060302u
#define LSEL 0x05040100u

__device__ __forceinline__ float ldbf(const void* p, int i) { return __bfloat162float(((const bf16*)p)[i]); }
__device__ __forceinline__ float ldf (const void* p, int i) { return ((const float*)p)[i]; }

__device__ __forceinline__ unsigned short f2bf(float x) {
    union { float f; u32 u; } a; a.f = x;
    u32 r = a.u + 0x7FFF + ((a.u >> 16) & 1);
    return (unsigned short)(r >> 16);
}
__device__ __forceinline__ float bf2f(unsigned short s) {
    union { u32 u; float f; } a; a.u = ((u32)s) << 16;
    return a.f;
}
__device__ __forceinline__ u32 packbf(float x) {
    unsigned short h = f2bf(x);
    unsigned short l = f2bf(x - bf2f(h));
    return ((u32)h << 16) | (u32)l;
}
__device__ __forceinline__ u32 okey(float f) {
    u32 u = __float_as_uint(f);
    return u ^ ((u & 0x80000000u) ? 0xFFFFFFFFu : 0x80000000u);
}
__device__ __forceinline__ float unokey(u32 k) {
    u32 u = (k & 0x80000000u) ? (k ^ 0x80000000u) : ~k;
    return __uint_as_float(u);
}
__device__ __forceinline__ int cntdim(int x) {
    int c = 0;
#pragma unroll
    for (int pp = 0; pp < 7; pp++) {
        int q = x - pp;
        c += (q >= 0 && q <= 92 && ((q & 3) == 0)) ? 1 : 0;
    }
    if (x == 95) c += 3;
    return c;
}

// per-block dtype vote (fp32 low-mantissa words decode to "insane" bf16 exponents)
__device__ __forceinline__ int detect_flag(const void* vid, int tid, int* sflag) {
    if (tid < 64) {
        unsigned short w = ((const unsigned short*)vid)[tid * 2];
        int e = (w >> 7) & 0xFF;
        int sane = ((e >= 100 && e <= 140) || ((w & 0x7FFF) == 0)) ? 1 : 0;
#pragma unroll
        for (int off = 1; off < 64; off <<= 1) sane += __shfl_xor(sane, off);
        if (tid == 0) *sflag = (sane >= 48) ? 1 : 0;
    }
    __syncthreads();
    return *sflag;
}

// ---------------- conv1x1 x3 + format conversion + ACC zero (R6-proven) ----------------
__global__ __launch_bounds__(256) void conv3_k(const void* vid, const void* gw, const void* gb,
                                               const void* tw, const void* tb, const void* pw,
                                               const void* pb,
                                               u32* __restrict__ B1p, __half* __restrict__ B2h,
                                               u32* __restrict__ B3p, float* __restrict__ ACCb)
{
    __shared__ float w[3120];
    __shared__ int sflag;
    int tid = threadIdx.x;
    int isbf = detect_flag(vid, tid, &sflag);
    if (isbf) {
        for (int i = tid; i < 3120; i += 256) {
            float v;
            if (i < 1024) v = ldbf(gw, i);
            else if (i < 2048) v = ldbf(tw, i - 1024);
            else if (i < 3072) v = ldbf(pw, i - 2048);
            else if (i < 3088) v = ldbf(gb, i - 3072);
            else if (i < 3104) v = ldbf(tb, i - 3088);
            else v = ldbf(pb, i - 3104);
            w[i] = v;
        }
    } else {
        for (int i = tid; i < 3120; i += 256) {
            float v;
            if (i < 1024) v = ldf(gw, i);
            else if (i < 2048) v = ldf(tw, i - 1024);
            else if (i < 3072) v = ldf(pw, i - 2048);
            else if (i < 3088) v = ldf(gb, i - 3072);
            else if (i < 3104) v = ldf(tb, i - 3088);
            else v = ldf(pb, i - 3104);
            w[i] = v;
        }
    }
    __syncthreads();

    {
        float4v z = {0.f, 0.f, 0.f, 0.f};
        *(float4v*)(ACCb + (blockIdx.x * 256 + tid) * 4) = z;
    }

    int lane = tid & 63, og = tid >> 6;
    int g0 = blockIdx.x * 64 + lane;          // 576*64 = 36864 exactly
    int t = g0 / HW_, pix = g0 - t * HW_;

    float a1[4], a2[4], a3[4];
#pragma unroll
    for (int k = 0; k < 4; k++) {
        a1[k] = w[3072 + og * 4 + k];
        a2[k] = w[3088 + og * 4 + k];
        a3[k] = w[3104 + og * 4 + k];
    }
    int base = t * C_ * HW_ + pix;
#pragma unroll 16
    for (int c = 0; c < C_; c++) {
        float v = isbf ? ldbf(vid, base + c * HW_) : ldf(vid, base + c * HW_);
#pragma unroll
        for (int k = 0; k < 4; k++) {
            a1[k] += v * w[(og * 4 + k) * 64 + c];
            a2[k] += v * w[1024 + (og * 4 + k) * 64 + c];
            a3[k] += v * w[2048 + (og * 4 + k) * 64 + c];
        }
    }
    int ob = g0 * 16 + og * 4;
    uint4 p1, p3;
    p1.x = packbf(a1[0]); p1.y = packbf(a1[1]); p1.z = packbf(a1[2]); p1.w = packbf(a1[3]);
    p3.x = packbf(a3[0]); p3.y = packbf(a3[1]); p3.z = packbf(a3[2]); p3.w = packbf(a3[3]);
    *(uint4*)(B1p + ob) = p1;
    *(uint4*)(B3p + ob) = p3;
    __half2 h01 = __floats2half2_rn(a2[0], a2[1]);
    __half2 h23 = __floats2half2_rn(a2[2], a2[3]);
    uint2 p2;
    p2.x = *(u32*)&h01; p2.y = *(u32*)&h23;
    *(uint2*)(B2h + ob) = p2;
}

// ---------------- fused attention: one block = 2x2 queries (R8 structure) ----------------
// PV plane is XOR-swizzled (col ^ (row&3)) to break the cell-mod-4 bank-group
// collapse (row stride 32 cells == 0 mod 4 put all pi rows in one group).
__global__ __launch_bounds__(256, 3) void attn_k(const u32* __restrict__ B1p,
                                                 const __half* __restrict__ B2h,
                                                 const u32* __restrict__ B3p,
                                                 float* __restrict__ ACCb)
{
    __shared__ __align__(16) char SM[47248];
    short*   Win  = (short*)SM;
    float*   Sc   = (float*)(SM + 32768);
    float*   Cb   = (float*)(SM + 39824);
    int*     hist = (int*)(SM + 39824);
    float*   yiw  = (float*)(SM + 43920);
    int*     pab  = (int*)(SM + 45520);
    int*     ctl  = (int*)(SM + 47120);
    __half2* Wp   = (__half2*)SM;

    int tid = threadIdx.x;
    int tile = blockIdx.x, t = blockIdx.y;
    int qy = tile / 12, qx = tile - qy * 12;
    int qi = qy * 8, qj = qx * 8;

    const u32*    B1t = B1p + t * HW_ * 16;
    const __half* B2t = B2h + t * HW_ * 16;
    const u32*    B3t = B3p + t * HW_ * 16;

    int lane = tid & 63, wv = tid >> 6;
    int nn = lane & 15, qsel = nn >> 3, pjn = nn & 7;
    int koff = (lane >> 4) * 8;

    // ---- stage h-plane: 32x32 window ----
    for (int pos = tid; pos < 1024; pos += 256) {
        int row = pos >> 5, col = pos & 31;
        int vr = min(max(qi - 10 + row, 0), 95);
        int vc = min(max(qj - 10 + col, 0), 95);
        const u32* src = B3t + (vr * 96 + vc) * 16;
        uint4 U0 = *(const uint4*)src,       U1 = *(const uint4*)(src + 4);
        uint4 U2 = *(const uint4*)(src + 8), U3 = *(const uint4*)(src + 12);
        uint4 A, B;
        A.x = __builtin_amdgcn_perm(U0.y, U0.x, HSEL);
        A.y = __builtin_amdgcn_perm(U0.w, U0.z, HSEL);
        A.z = __builtin_amdgcn_perm(U1.y, U1.x, HSEL);
        A.w = __builtin_amdgcn_perm(U1.w, U1.z, HSEL);
        B.x = __builtin_amdgcn_perm(U2.y, U2.x, HSEL);
        B.y = __builtin_amdgcn_perm(U2.w, U2.z, HSEL);
        B.z = __builtin_amdgcn_perm(U3.y, U3.x, HSEL);
        B.w = __builtin_amdgcn_perm(U3.w, U3.z, HSEL);
        *(uint4*)(Win + pos * 16)     = A;
        *(uint4*)(Win + pos * 16 + 8) = B;
    }
    __syncthreads();

    // ---- score phase A: Ah*Bh + Ah*Bl, query rows ri = 0,1 ----
#pragma unroll 1
    for (int ri = 0; ri < 2; ri++) {
        short8 Bh[4], Bl[4];
        int qiq = qi + 4 * ri, qjq = qj + 4 * qsel;
#pragma unroll
        for (int s = 0; s < 4; s++) {
            int kk0 = s * 32 + koff;
            int pi = kk0 >> 4, c0 = kk0 & 15;
            uint4 U0 = {0, 0, 0, 0}, U1 = {0, 0, 0, 0};
            if (pjn < 7 && pi < 7) {
                const u32* src = B1t + (min(qiq + pi, 95) * 96 + min(qjq + pjn, 95)) * 16 + c0;
                U0 = *(const uint4*)src;
                U1 = *(const uint4*)(src + 4);
            }
            union { uint4 u; short8 s8; } hc, lc;
            hc.u.x = __builtin_amdgcn_perm(U0.y, U0.x, HSEL);
            hc.u.y = __builtin_amdgcn_perm(U0.w, U0.z, HSEL);
            hc.u.z = __builtin_amdgcn_perm(U1.y, U1.x, HSEL);
            hc.u.w = __builtin_amdgcn_perm(U1.w, U1.z, HSEL);
            lc.u.x = __builtin_amdgcn_perm(U0.y, U0.x, LSEL);
            lc.u.y = __builtin_amdgcn_perm(U0.w, U0.z, LSEL);
            lc.u.z = __builtin_amdgcn_perm(U1.y, U1.x, LSEL);
            lc.u.w = __builtin_amdgcn_perm(U1.w, U1.z, LSEL);
            Bh[s] = hc.s8; Bl[s] = lc.s8;
        }
        float* Cw = Cb + wv * 256;
        for (int r = wv; r < 21; r += 4) {
            float psum = 0.f;
            int v = (lane >= 21) ? 1 : 0;
            int b = lane - v * 21;
#pragma unroll
            for (int st = 0; st < 2; st++) {
                float4v acc = {0.f, 0.f, 0.f, 0.f};
#pragma unroll
                for (int s = 0; s < 4; s++) {
                    int arow = 4 * ri + r + 2 * s + (lane >> 5);
                    int aoff = (arow * 32 + st * 16 + nn) * 16 + ((lane >> 4) & 1) * 8;
                    short8 A = *(const short8*)(Win + aoff);
                    acc = __builtin_amdgcn_mfma_f32_16x16x32_bf16(A, Bh[s], acc, 0, 0, 0);
                    acc = __builtin_amdgcn_mfma_f32_16x16x32_bf16(A, Bl[s], acc, 0, 0, 0);
                }
                *(float4v*)(Cw + nn * 16 + (lane >> 4) * 4) = acc;
                if (lane < 42) {
#pragma unroll
                    for (int pj = 0; pj < 7; pj++) {
                        int sp = b + 4 * v + pj;
                        if ((sp >> 4) == st) psum += Cw[(8 * v + pj) * 16 + (sp & 15)];
                    }
                }
            }
            if (lane < 42) Sc[(ri * 2 + v) * 441 + r * 21 + b] = psum;
        }
    }
    __syncthreads();

    // ---- stage l-plane (same packed source, L1-hot) ----
    for (int pos = tid; pos < 1024; pos += 256) {
        int row = pos >> 5, col = pos & 31;
        int vr = min(max(qi - 10 + row, 0), 95);
        int vc = min(max(qj - 10 + col, 0), 95);
        const u32* src = B3t + (vr * 96 + vc) * 16;
        uint4 U0 = *(const uint4*)src,       U1 = *(const uint4*)(src + 4);
        uint4 U2 = *(const uint4*)(src + 8), U3 = *(const uint4*)(src + 12);
        uint4 A, B;
        A.x = __builtin_amdgcn_perm(U0.y, U0.x, LSEL);
        A.y = __builtin_amdgcn_perm(U0.w, U0.z, LSEL);
        A.z = __builtin_amdgcn_perm(U1.y, U1.x, LSEL);
        A.w = __builtin_amdgcn_perm(U1.w, U1.z, LSEL);
        B.x = __builtin_amdgcn_perm(U2.y, U2.x, LSEL);
        B.y = __builtin_amdgcn_perm(U2.w, U2.z, LSEL);
        B.z = __builtin_amdgcn_perm(U3.y, U3.x, LSEL);
        B.w = __builtin_amdgcn_perm(U3.w, U3.z, LSEL);
        *(uint4*)(Win + pos * 16)     = A;
        *(uint4*)(Win + pos * 16 + 8) = B;
    }
    __syncthreads();

    // ---- score phase B: Sc += Al*Bh ----
#pragma unroll 1
    for (int ri = 0; ri < 2; ri++) {
        short8 Bh[4];
        int qiq = qi + 4 * ri, qjq = qj + 4 * qsel;
#pragma unroll
        for (int s = 0; s < 4; s++) {
            int kk0 = s * 32 + koff;
            int pi = kk0 >> 4, c0 = kk0 & 15;
            uint4 U0 = {0, 0, 0, 0}, U1 = {0, 0, 0, 0};
            if (pjn < 7 && pi < 7) {
                const u32* src = B1t + (min(qiq + pi, 95) * 96 + min(qjq + pjn, 95)) * 16 + c0;
                U0 = *(const uint4*)src;
                U1 = *(const uint4*)(src + 4);
            }
            union { uint4 u; short8 s8; } hc;
            hc.u.x = __builtin_amdgcn_perm(U0.y, U0.x, HSEL);
            hc.u.y = __builtin_amdgcn_perm(U0.w, U0.z, HSEL);
            hc.u.z = __builtin_amdgcn_perm(U1.y, U1.x, HSEL);
            hc.u.w = __builtin_amdgcn_perm(U1.w, U1.z, HSEL);
            Bh[s] = hc.s8;
        }
        float* Cw = Cb + wv * 256;
        for (int r = wv; r < 21; r += 4) {
            float psum = 0.f;
            int v = (lane >= 21) ? 1 : 0;
            int b = lane - v * 21;
#pragma unroll
            for (int st = 0; st < 2; st++) {
                float4v acc = {0.f, 0.f, 0.f, 0.f};
#pragma unroll
                for (int s = 0; s < 4; s++) {
                    int arow = 4 * ri + r + 2 * s + (lane >> 5);
                    int aoff = (arow * 32 + st * 16 + nn) * 16 + ((lane >> 4) & 1) * 8;
                    short8 A = *(const short8*)(Win + aoff);
                    acc = __builtin_amdgcn_mfma_f32_16x16x32_bf16(A, Bh[s], acc, 0, 0, 0);
                }
                *(float4v*)(Cw + nn * 16 + (lane >> 4) * 4) = acc;
                if (lane < 42) {
#pragma unroll
                    for (int pj = 0; pj < 7; pj++) {
                        int sp = b + 4 * v + pj;
                        if ((sp >> 4) == st) psum += Cw[(8 * v + pj) * 16 + (sp & 15)];
                    }
                }
            }
            if (lane < 42) Sc[(ri * 2 + v) * 441 + r * 21 + b] += psum;
        }
    }
    __syncthreads();

    // ---- fixup border dups + stage PV f16 plane (XOR-swizzled) + init hist/ctl ----
    for (int idx = tid; idx < 1764; idx += 256) {
        int g = idx / 441, k = idx - g * 441;
        int a = k / 21, b = k - a * 21;
        int ri = g >> 1, ci = g & 1;
        int qiq = qi + 4 * ri, qjq = qj + 4 * ci;
        int alo = max(0, 10 - qiq), ahi = min(20, 105 - qiq);
        int blo = max(0, 10 - qjq), bhi = min(20, 105 - qjq);
        int ae = min(max(a, alo), ahi), be = min(max(b, blo), bhi);
        if (ae != a || be != b) Sc[g * 441 + k] = Sc[g * 441 + ae * 21 + be];
    }
    for (int pos = tid; pos < 992; pos += 256) {
        int row = pos >> 5, col = pos & 31;
        int vr = min(max(qi - 10 + row, 0), 95);
        int vc = min(max(qj - 10 + col, 0), 95);
        const __half* src = B2t + (vr * 96 + vc) * 16;
        int cell = row * 32 + (col ^ (row & 3));      // bank-group swizzle
        *(int4*)(Wp + cell * 8)     = *(const int4*)src;
        *(int4*)(Wp + cell * 8 + 4) = *(const int4*)(src + 8);
    }
    hist[tid] = 0; hist[256 + tid] = 0; hist[512 + tid] = 0; hist[768 + tid] = 0;
    if (tid < 32) ctl[tid] = ((tid & 7) == 1) ? K_ : 0;
    __syncthreads();

    // ---- adaptive radix-256 exact top-100: one wave per query ----
    int g = wv;
    u32 kreg[7]; int ni = 0;
    u32 kmax = 0;
    for (int i = lane; i < NC_; i += 64) {
        u32 k = okey(Sc[g * 441 + i]);
        kmax = max(kmax, k);
        kreg[ni++] = k;
    }
#pragma unroll
    for (int off = 1; off < 64; off <<= 1) kmax = max(kmax, (u32)__shfl_xor((int)kmax, off));

    for (int ps = 3; ps >= 0; ps--) {
        u32 pref = (u32)ctl[g * 8];
        if (!ctl[g * 8 + 3]) {
            for (int a = 0; a < ni; a++) {
                u32 k = kreg[a];
                if (ps == 3 || (k >> ((ps + 1) * 8)) == pref)
                    atomicAdd(&hist[g * 256 + ((k >> (ps * 8)) & 255)], 1);
            }
        }
        __syncthreads();
        if (!ctl[g * 8 + 3]) {
            int4 hv = *(int4*)(hist + g * 256 + lane * 4);
            int local = hv.x + hv.y + hv.z + hv.w;
            int s = local;
#pragma unroll
            for (int off = 1; off < 64; off <<= 1) {
                int tt = __shfl_down(s, off);
                if (lane + off < 64) s += tt;
            }
            int c4 = s - local;
            int c3 = c4 + hv.w, c2 = c3 + hv.z, c1 = c2 + hv.y, c0 = s;
            int need = ctl[g * 8 + 1];
            u32 pf = (u32)ctl[g * 8];
            int cums[5] = {c0, c1, c2, c3, c4};
            int hk[4] = {hv.x, hv.y, hv.z, hv.w};
#pragma unroll
            for (int k = 0; k < 4; k++) {
                if (cums[k] >= need && cums[k + 1] < need) {
                    int newneed = need - cums[k + 1];
                    ctl[g * 8]     = (int)((pf << 8) | (u32)(lane * 4 + k));
                    ctl[g * 8 + 1] = newneed;
                    if (newneed == hk[k] || ps == 0) { ctl[g * 8 + 3] = 1; ctl[g * 8 + 2] = 8 * ps; }
                }
            }
            int4 zz = {0, 0, 0, 0};
            *(int4*)(hist + g * 256 + lane * 4) = zz;
        }
        __syncthreads();
        if (ctl[3] && ctl[11] && ctl[19] && ctl[27]) break;
    }

    // ---- selection (wave-private; ties are interchangeable bitwise dups) ----
    int ri = g >> 1, ci = g & 1;
    int qiq = qi + 4 * ri, qjq = qj + 4 * ci;
    {
        u32 theta = (u32)ctl[g * 8];
        int shift = ctl[g * 8 + 2];
        int need  = ctl[g * 8 + 1];
        int base  = K_ - need;
        int alo = max(0, 10 - qiq), ahi = min(20, 105 - qiq);
        int blo = max(0, 10 - qjq), bhi = min(20, 105 - qjq);
        int a2 = 0;
        for (int i = lane; i < NC_; i += 64) {
            u32 k = kreg[a2++];
            u32 hp = k >> shift;
            int slot = -1;
            if (hp > theta) slot = atomicAdd(&ctl[g * 8 + 4], 1);
            else if (hp == theta) {
                int j = atomicAdd(&ctl[g * 8 + 5], 1);
                if (j < need) slot = base + j;
            }
            if (slot >= 0) {
                int a = i / 21, b = i - a * 21;
                int ae = min(max(a, alo), ahi), be = min(max(b, blo), bhi);
                yiw[g * 100 + slot] = Sc[g * 441 + i];
                pab[g * 100 + slot] = ((ae + 4 * ri) << 8) | (be + 4 * ci);
            }
        }
    }
    // ---- softmax (wave-private) ----
    {
        float m = unokey(kmax);
        float wa = expf((yiw[g * 100 + lane] - m) * 10.f);
        float wb2 = (lane < 36) ? expf((yiw[g * 100 + 64 + lane] - m) * 10.f) : 0.f;
        float ssum = wa + wb2;
#pragma unroll
        for (int off = 1; off < 64; off <<= 1) ssum += __shfl_xor(ssum, off);
        float inv = 1.f / ssum;
        yiw[g * 100 + lane] = wa * inv;
        if (lane < 36) yiw[g * 100 + 64 + lane] = wb2 * inv;
    }

    // ---- PV: wave owns its query; swizzled reads; channel-major atomics ----
    if (lane < 49) {
        int pi = lane / 7, pj = lane - pi * 7;
        int rsel = lane & 1;
        __half2 z[8];
#pragma unroll
        for (int j = 0; j < 8; j++) z[j] = __float2half2_rn(0.f);
        for (int k = 0; k < K_; k++) {
            float y = yiw[g * 100 + k];
            int pp = pab[g * 100 + k];
            int row = (pp >> 8) + pi, col = (pp & 255) + pj;
            int cell = row * 32 + (col ^ (row & 3));   // match staging swizzle
            const __half2* cellp = Wp + cell * 8;
            int4 A0 = *(const int4*)(cellp + rsel * 4);
            int4 A1 = *(const int4*)(cellp + 4 - rsel * 4);
            const __half2* pa = (const __half2*)&A0;
            const __half2* pb2 = (const __half2*)&A1;
            __half2 yh = __float2half2_rn(y);
#pragma unroll
            for (int j = 0; j < 4; j++) {
                z[j]     = __hfma2(pa[j],  yh, z[j]);
                z[4 + j] = __hfma2(pb2[j], yh, z[4 + j]);
            }
        }
        int orow = min(qiq + pi, 95), ocol = min(qjq + pj, 95);
        float* dst = ACCb + t * CI_ * HW_ + orow * 96 + ocol;
        int c0 = rsel * 8, c1 = 8 - c0;
#pragma unroll
        for (int jh = 0; jh < 4; jh++) {
            atomicAdd(dst + (c0 + 2 * jh) * HW_,     __low2float(z[jh]));
            atomicAdd(dst + (c0 + 2 * jh + 1) * HW_, __high2float(z[jh]));
            atomicAdd(dst + (c1 + 2 * jh) * HW_,     __low2float(z[4 + jh]));
            atomicAdd(dst + (c1 + 2 * jh + 1) * HW_, __high2float(z[4 + jh]));
        }
    }
}

// ---------------- final: y = ACC/Z (Z analytic), conv1x1 + residual ----------------
__global__ __launch_bounds__(256) void out_k(const void* vid, const void* Ww, const void* Wb,
                                             const float* __restrict__ ACCb, void* out)
{
    __shared__ float w[1088];
    __shared__ int sflag;
    int tid = threadIdx.x;
    int isbf = detect_flag(vid, tid, &sflag);
    if (isbf) { for (int i = tid; i < 1088; i += 256) w[i] = (i < 1024) ? ldbf(Ww, i) : ldbf(Wb, i - 1024); }
    else      { for (int i = tid; i < 1088; i += 256) w[i] = (i < 1024) ? ldf (Ww, i) : ldf (Wb, i - 1024); }
    __syncthreads();

    int lane5 = tid & 31, oct = tid >> 5;
    int g0 = blockIdx.x * 32 + lane5;           // 1152*32 = 36864 exactly
    int t = g0 / HW_, pix = g0 - t * HW_;
    int pi = pix / 96, pj = pix - pi * 96;
    float invz = 1.f / (float)(cntdim(pi) * cntdim(pj));

    float y[CI_];
    int ab = t * CI_ * HW_ + pix;
#pragma unroll
    for (int ci = 0; ci < CI_; ci++) y[ci] = ACCb[ab + ci * HW_] * invz;

    int vb = t * C_ * HW_ + pix;
#pragma unroll
    for (int co = oct * 8; co < oct * 8 + 8; co++) {
        float s = w[1024 + co];
#pragma unroll
        for (int ci = 0; ci < CI_; ci++) s += w[co * 16 + ci] * y[ci];
        int idx = vb + co * HW_;
        float vv = isbf ? ldbf(vid, idx) : ldf(vid, idx);
        float r = vv + s;
        if (isbf) ((bf16*)out)[idx] = __float2bfloat16(r);
        else      ((float*)out)[idx] = r;
    }
}

extern "C" void kernel_launch(void* const* d_in, const int* in_sizes, int n_in,
                              void* d_out, int out_size, void* d_ws, size_t ws_size,
                              hipStream_t stream)
{
    // ws byte layout: B1p @0, B2h @2359296, B3p @3538944, ACC @5898240
    char* ws = (char*)d_ws;
    u32*    B1p  = (u32*)ws;
    __half* B2h  = (__half*)(ws + 2359296);
    u32*    B3p  = (u32*)(ws + 3538944);
    float*  ACCb = (float*)(ws + 5898240);

    conv3_k<<<dim3(576), dim3(256), 0, stream>>>(d_in[0], d_in[1], d_in[2], d_in[3], d_in[4],
                                                 d_in[5], d_in[6], B1p, B2h, B3p, ACCb);
    attn_k<<<dim3(144, T_), dim3(256), 0, stream>>>(B1p, B2h, B3p, ACCb);
    out_k<<<dim3(1152), dim3(256), 0, stream>>>(d_in[0], d_in[7], d_in[8], ACCb, d_out);
}

// Round 12
// 181.882 us; speedup vs baseline: 1.2120x; 1.0031x over previous
//
#include <hip/hip_runtime.h>
#include <hip/hip_bf16.h>
#include <hip/hip_fp16.h>
#include <math.h>

typedef __hip_bfloat16 bf16;
typedef unsigned int u32;
typedef __attribute__((ext_vector_type(8))) short short8;
typedef __attribute__((ext_vector_type(4))) float float4v;

#define T_   4
#define C_   64
#define H_   96
#define W_   96
#define CI_  16
#define HW_  9216
#define NC_  441
#define K_   100
#define HSEL 0x07060302u
#define LSEL 0x05040100u

__device__ __forceinline__ float ldbf(const void* p, int i) { return __bfloat162float(((const bf16*)p)[i]); }
__device__ __forceinline__ float ldf (const void* p, int i) { return ((const float*)p)[i]; }

__device__ __forceinline__ unsigned short f2bf(float x) {
    union { float f; u32 u; } a; a.f = x;
    u32 r = a.u + 0x7FFF + ((a.u >> 16) & 1);
    return (unsigned short)(r >> 16);
}
__device__ __forceinline__ float bf2f(unsigned short s) {
    union { u32 u; float f; } a; a.u = ((u32)s) << 16;
    return a.f;
}
__device__ __forceinline__ u32 packbf(float x) {
    unsigned short h = f2bf(x);
    unsigned short l = f2bf(x - bf2f(h));
    return ((u32)h << 16) | (u32)l;
}
__device__ __forceinline__ u32 okey(float f) {
    u32 u = __float_as_uint(f);
    return u ^ ((u & 0x80000000u) ? 0xFFFFFFFFu : 0x80000000u);
}
__device__ __forceinline__ float unokey(u32 k) {
    u32 u = (k & 0x80000000u) ? (k ^ 0x80000000u) : ~k;
    return __uint_as_float(u);
}
__device__ __forceinline__ int cntdim(int x) {
    int c = 0;
#pragma unroll
    for (int pp = 0; pp < 7; pp++) {
        int q = x - pp;
        c += (q >= 0 && q <= 92 && ((q & 3) == 0)) ? 1 : 0;
    }
    if (x == 95) c += 3;
    return c;
}

// per-block dtype vote (fp32 low-mantissa words decode to "insane" bf16 exponents)
__device__ __forceinline__ int detect_flag(const void* vid, int tid, int* sflag) {
    if (tid < 64) {
        unsigned short w = ((const unsigned short*)vid)[tid * 2];
        int e = (w >> 7) & 0xFF;
        int sane = ((e >= 100 && e <= 140) || ((w & 0x7FFF) == 0)) ? 1 : 0;
#pragma unroll
        for (int off = 1; off < 64; off <<= 1) sane += __shfl_xor(sane, off);
        if (tid == 0) *sflag = (sane >= 48) ? 1 : 0;
    }
    __syncthreads();
    return *sflag;
}

// ---------------- conv1x1 x3 + format conversion + ACC zero (R6-proven) ----------------
__global__ __launch_bounds__(256) void conv3_k(const void* vid, const void* gw, const void* gb,
                                               const void* tw, const void* tb, const void* pw,
                                               const void* pb,
                                               u32* __restrict__ B1p, __half* __restrict__ B2h,
                                               u32* __restrict__ B3p, float* __restrict__ ACCb)
{
    __shared__ float w[3120];
    __shared__ int sflag;
    int tid = threadIdx.x;
    int isbf = detect_flag(vid, tid, &sflag);
    if (isbf) {
        for (int i = tid; i < 3120; i += 256) {
            float v;
            if (i < 1024) v = ldbf(gw, i);
            else if (i < 2048) v = ldbf(tw, i - 1024);
            else if (i < 3072) v = ldbf(pw, i - 2048);
            else if (i < 3088) v = ldbf(gb, i - 3072);
            else if (i < 3104) v = ldbf(tb, i - 3088);
            else v = ldbf(pb, i - 3104);
            w[i] = v;
        }
    } else {
        for (int i = tid; i < 3120; i += 256) {
            float v;
            if (i < 1024) v = ldf(gw, i);
            else if (i < 2048) v = ldf(tw, i - 1024);
            else if (i < 3072) v = ldf(pw, i - 2048);
            else if (i < 3088) v = ldf(gb, i - 3072);
            else if (i < 3104) v = ldf(tb, i - 3088);
            else v = ldf(pb, i - 3104);
            w[i] = v;
        }
    }
    __syncthreads();

    {
        float4v z = {0.f, 0.f, 0.f, 0.f};
        *(float4v*)(ACCb + (blockIdx.x * 256 + tid) * 4) = z;
    }

    int lane = tid & 63, og = tid >> 6;
    int g0 = blockIdx.x * 64 + lane;          // 576*64 = 36864 exactly
    int t = g0 / HW_, pix = g0 - t * HW_;

    float a1[4], a2[4], a3[4];
#pragma unroll
    for (int k = 0; k < 4; k++) {
        a1[k] = w[3072 + og * 4 + k];
        a2[k] = w[3088 + og * 4 + k];
        a3[k] = w[3104 + og * 4 + k];
    }
    int base = t * C_ * HW_ + pix;
#pragma unroll 16
    for (int c = 0; c < C_; c++) {
        float v = isbf ? ldbf(vid, base + c * HW_) : ldf(vid, base + c * HW_);
#pragma unroll
        for (int k = 0; k < 4; k++) {
            a1[k] += v * w[(og * 4 + k) * 64 + c];
            a2[k] += v * w[1024 + (og * 4 + k) * 64 + c];
            a3[k] += v * w[2048 + (og * 4 + k) * 64 + c];
        }
    }
    int ob = g0 * 16 + og * 4;
    uint4 p1, p3;
    p1.x = packbf(a1[0]); p1.y = packbf(a1[1]); p1.z = packbf(a1[2]); p1.w = packbf(a1[3]);
    p3.x = packbf(a3[0]); p3.y = packbf(a3[1]); p3.z = packbf(a3[2]); p3.w = packbf(a3[3]);
    *(uint4*)(B1p + ob) = p1;
    *(uint4*)(B3p + ob) = p3;
    __half2 h01 = __floats2half2_rn(a2[0], a2[1]);
    __half2 h23 = __floats2half2_rn(a2[2], a2[3]);
    uint2 p2;
    p2.x = *(u32*)&h01; p2.y = *(u32*)&h23;
    *(uint2*)(B2h + ob) = p2;
}

// ---------------- fused attention: one block = 2x2 queries (R8/R10-proven core) ----------------
// bf16 3-term score (Ah*Bh + Ah*Bl + Al*Bh), per-wave radix-256 exact top-100 with
// the border-clip remap folded into the key gather (identical key multiset ->
// identical jax tie semantics; selection values reconstructed bitwise via unokey).
__global__ __launch_bounds__(256, 3) void attn_k(const u32* __restrict__ B1p,
                                                 const __half* __restrict__ B2h,
                                                 const u32* __restrict__ B3p,
                                                 float* __restrict__ ACCb)
{
    __shared__ __align__(16) char SM[47248];
    short*   Win  = (short*)SM;
    float*   Sc   = (float*)(SM + 32768);
    float*   Cb   = (float*)(SM + 39824);
    int*     hist = (int*)(SM + 39824);
    float*   yiw  = (float*)(SM + 43920);
    int*     pab  = (int*)(SM + 45520);
    int*     ctl  = (int*)(SM + 47120);
    __half2* Wp   = (__half2*)SM;

    int tid = threadIdx.x;
    int tile = blockIdx.x, t = blockIdx.y;
    int qy = tile / 12, qx = tile - qy * 12;
    int qi = qy * 8, qj = qx * 8;

    const u32*    B1t = B1p + t * HW_ * 16;
    const __half* B2t = B2h + t * HW_ * 16;
    const u32*    B3t = B3p + t * HW_ * 16;

    int lane = tid & 63, wv = tid >> 6;
    int nn = lane & 15, qsel = nn >> 3, pjn = nn & 7;
    int koff = (lane >> 4) * 8;

    // ---- stage h-plane: 32x32 window ----
    for (int pos = tid; pos < 1024; pos += 256) {
        int row = pos >> 5, col = pos & 31;
        int vr = min(max(qi - 10 + row, 0), 95);
        int vc = min(max(qj - 10 + col, 0), 95);
        const u32* src = B3t + (vr * 96 + vc) * 16;
        uint4 U0 = *(const uint4*)src,       U1 = *(const uint4*)(src + 4);
        uint4 U2 = *(const uint4*)(src + 8), U3 = *(const uint4*)(src + 12);
        uint4 A, B;
        A.x = __builtin_amdgcn_perm(U0.y, U0.x, HSEL);
        A.y = __builtin_amdgcn_perm(U0.w, U0.z, HSEL);
        A.z = __builtin_amdgcn_perm(U1.y, U1.x, HSEL);
        A.w = __builtin_amdgcn_perm(U1.w, U1.z, HSEL);
        B.x = __builtin_amdgcn_perm(U2.y, U2.x, HSEL);
        B.y = __builtin_amdgcn_perm(U2.w, U2.z, HSEL);
        B.z = __builtin_amdgcn_perm(U3.y, U3.x, HSEL);
        B.w = __builtin_amdgcn_perm(U3.w, U3.z, HSEL);
        *(uint4*)(Win + pos * 16)     = A;
        *(uint4*)(Win + pos * 16 + 8) = B;
    }
    __syncthreads();

    // ---- score phase A: Ah*Bh + Ah*Bl, query rows ri = 0,1 ----
#pragma unroll 1
    for (int ri = 0; ri < 2; ri++) {
        short8 Bh[4], Bl[4];
        int qiq = qi + 4 * ri, qjq = qj + 4 * qsel;
#pragma unroll
        for (int s = 0; s < 4; s++) {
            int kk0 = s * 32 + koff;
            int pi = kk0 >> 4, c0 = kk0 & 15;
            uint4 U0 = {0, 0, 0, 0}, U1 = {0, 0, 0, 0};
            if (pjn < 7 && pi < 7) {
                const u32* src = B1t + (min(qiq + pi, 95) * 96 + min(qjq + pjn, 95)) * 16 + c0;
                U0 = *(const uint4*)src;
                U1 = *(const uint4*)(src + 4);
            }
            union { uint4 u; short8 s8; } hc, lc;
            hc.u.x = __builtin_amdgcn_perm(U0.y, U0.x, HSEL);
            hc.u.y = __builtin_amdgcn_perm(U0.w, U0.z, HSEL);
            hc.u.z = __builtin_amdgcn_perm(U1.y, U1.x, HSEL);
            hc.u.w = __builtin_amdgcn_perm(U1.w, U1.z, HSEL);
            lc.u.x = __builtin_amdgcn_perm(U0.y, U0.x, LSEL);
            lc.u.y = __builtin_amdgcn_perm(U0.w, U0.z, LSEL);
            lc.u.z = __builtin_amdgcn_perm(U1.y, U1.x, LSEL);
            lc.u.w = __builtin_amdgcn_perm(U1.w, U1.z, LSEL);
            Bh[s] = hc.s8; Bl[s] = lc.s8;
        }
        float* Cw = Cb + wv * 256;
        for (int r = wv; r < 21; r += 4) {
            float psum = 0.f;
            int v = (lane >= 21) ? 1 : 0;
            int b = lane - v * 21;
#pragma unroll
            for (int st = 0; st < 2; st++) {
                float4v acc = {0.f, 0.f, 0.f, 0.f};
#pragma unroll
                for (int s = 0; s < 4; s++) {
                    int arow = 4 * ri + r + 2 * s + (lane >> 5);
                    int aoff = (arow * 32 + st * 16 + nn) * 16 + ((lane >> 4) & 1) * 8;
                    short8 A = *(const short8*)(Win + aoff);
                    acc = __builtin_amdgcn_mfma_f32_16x16x32_bf16(A, Bh[s], acc, 0, 0, 0);
                    acc = __builtin_amdgcn_mfma_f32_16x16x32_bf16(A, Bl[s], acc, 0, 0, 0);
                }
                *(float4v*)(Cw + nn * 16 + (lane >> 4) * 4) = acc;
                if (lane < 42) {
#pragma unroll
                    for (int pj = 0; pj < 7; pj++) {
                        int sp = b + 4 * v + pj;
                        if ((sp >> 4) == st) psum += Cw[(8 * v + pj) * 16 + (sp & 15)];
                    }
                }
            }
            if (lane < 42) Sc[(ri * 2 + v) * 441 + r * 21 + b] = psum;
        }
    }
    __syncthreads();

    // ---- stage l-plane (same packed source, L1-hot) ----
    for (int pos = tid; pos < 1024; pos += 256) {
        int row = pos >> 5, col = pos & 31;
        int vr = min(max(qi - 10 + row, 0), 95);
        int vc = min(max(qj - 10 + col, 0), 95);
        const u32* src = B3t + (vr * 96 + vc) * 16;
        uint4 U0 = *(const uint4*)src,       U1 = *(const uint4*)(src + 4);
        uint4 U2 = *(const uint4*)(src + 8), U3 = *(const uint4*)(src + 12);
        uint4 A, B;
        A.x = __builtin_amdgcn_perm(U0.y, U0.x, LSEL);
        A.y = __builtin_amdgcn_perm(U0.w, U0.z, LSEL);
        A.z = __builtin_amdgcn_perm(U1.y, U1.x, LSEL);
        A.w = __builtin_amdgcn_perm(U1.w, U1.z, LSEL);
        B.x = __builtin_amdgcn_perm(U2.y, U2.x, LSEL);
        B.y = __builtin_amdgcn_perm(U2.w, U2.z, LSEL);
        B.z = __builtin_amdgcn_perm(U3.y, U3.x, LSEL);
        B.w = __builtin_amdgcn_perm(U3.w, U3.z, LSEL);
        *(uint4*)(Win + pos * 16)     = A;
        *(uint4*)(Win + pos * 16 + 8) = B;
    }
    __syncthreads();

    // ---- score phase B: Sc += Al*Bh ----
#pragma unroll 1
    for (int ri = 0; ri < 2; ri++) {
        short8 Bh[4];
        int qiq = qi + 4 * ri, qjq = qj + 4 * qsel;
#pragma unroll
        for (int s = 0; s < 4; s++) {
            int kk0 = s * 32 + koff;
            int pi = kk0 >> 4, c0 = kk0 & 15;
            uint4 U0 = {0, 0, 0, 0}, U1 = {0, 0, 0, 0};
            if (pjn < 7 && pi < 7) {
                const u32* src = B1t + (min(qiq + pi, 95) * 96 + min(qjq + pjn, 95)) * 16 + c0;
                U0 = *(const uint4*)src;
                U1 = *(const uint4*)(src + 4);
            }
            union { uint4 u; short8 s8; } hc;
            hc.u.x = __builtin_amdgcn_perm(U0.y, U0.x, HSEL);
            hc.u.y = __builtin_amdgcn_perm(U0.w, U0.z, HSEL);
            hc.u.z = __builtin_amdgcn_perm(U1.y, U1.x, HSEL);
            hc.u.w = __builtin_amdgcn_perm(U1.w, U1.z, HSEL);
            Bh[s] = hc.s8;
        }
        float* Cw = Cb + wv * 256;
        for (int r = wv; r < 21; r += 4) {
            float psum = 0.f;
            int v = (lane >= 21) ? 1 : 0;
            int b = lane - v * 21;
#pragma unroll
            for (int st = 0; st < 2; st++) {
                float4v acc = {0.f, 0.f, 0.f, 0.f};
#pragma unroll
                for (int s = 0; s < 4; s++) {
                    int arow = 4 * ri + r + 2 * s + (lane >> 5);
                    int aoff = (arow * 32 + st * 16 + nn) * 16 + ((lane >> 4) & 1) * 8;
                    short8 A = *(const short8*)(Win + aoff);
                    acc = __builtin_amdgcn_mfma_f32_16x16x32_bf16(A, Bh[s], acc, 0, 0, 0);
                }
                *(float4v*)(Cw + nn * 16 + (lane >> 4) * 4) = acc;
                if (lane < 42) {
#pragma unroll
                    for (int pj = 0; pj < 7; pj++) {
                        int sp = b + 4 * v + pj;
                        if ((sp >> 4) == st) psum += Cw[(8 * v + pj) * 16 + (sp & 15)];
                    }
                }
            }
            if (lane < 42) Sc[(ri * 2 + v) * 441 + r * 21 + b] += psum;
        }
    }
    __syncthreads();

    // ---- stage PV f16 plane + init hist/ctl (fixup folded into key gather below) ----
    for (int pos = tid; pos < 992; pos += 256) {
        int row = pos >> 5, col = pos & 31;
        int vr = min(max(qi - 10 + row, 0), 95);
        int vc = min(max(qj - 10 + col, 0), 95);
        const __half* src = B2t + (vr * 96 + vc) * 16;
        *(int4*)(Wp + pos * 8)     = *(const int4*)src;
        *(int4*)(Wp + pos * 8 + 4) = *(const int4*)(src + 8);
    }
    hist[tid] = 0; hist[256 + tid] = 0; hist[512 + tid] = 0; hist[768 + tid] = 0;
    if (tid < 32) ctl[tid] = ((tid & 7) == 1) ? K_ : 0;
    __syncthreads();

    // ---- adaptive radix-256 exact top-100: one wave per query; clip-remapped keys ----
    int g = wv;
    int ri = g >> 1, ci = g & 1;
    int qiq = qi + 4 * ri, qjq = qj + 4 * ci;
    int alo = max(0, 10 - qiq), ahi = min(20, 105 - qiq);
    int blo = max(0, 10 - qjq), bhi = min(20, 105 - qjq);
    u32 kreg[7]; int ni = 0;
    u32 kmax = 0;
    for (int i = lane; i < NC_; i += 64) {
        int aa = i / 21, bb = i - aa * 21;
        int ae = min(max(aa, alo), ahi), be = min(max(bb, blo), bhi);
        u32 k = okey(Sc[g * 441 + ae * 21 + be]);
        kmax = max(kmax, k);
        kreg[ni++] = k;
    }
#pragma unroll
    for (int off = 1; off < 64; off <<= 1) kmax = max(kmax, (u32)__shfl_xor((int)kmax, off));

    for (int ps = 3; ps >= 0; ps--) {
        u32 pref = (u32)ctl[g * 8];
        if (!ctl[g * 8 + 3]) {
            for (int a = 0; a < ni; a++) {
                u32 k = kreg[a];
                if (ps == 3 || (k >> ((ps + 1) * 8)) == pref)
                    atomicAdd(&hist[g * 256 + ((k >> (ps * 8)) & 255)], 1);
            }
        }
        __syncthreads();
        if (!ctl[g * 8 + 3]) {
            int4 hv = *(int4*)(hist + g * 256 + lane * 4);
            int local = hv.x + hv.y + hv.z + hv.w;
            int s = local;
#pragma unroll
            for (int off = 1; off < 64; off <<= 1) {
                int tt = __shfl_down(s, off);
                if (lane + off < 64) s += tt;
            }
            int c4 = s - local;
            int c3 = c4 + hv.w, c2 = c3 + hv.z, c1 = c2 + hv.y, c0 = s;
            int need = ctl[g * 8 + 1];
            u32 pf = (u32)ctl[g * 8];
            int cums[5] = {c0, c1, c2, c3, c4};
            int hk[4] = {hv.x, hv.y, hv.z, hv.w};
#pragma unroll
            for (int k = 0; k < 4; k++) {
                if (cums[k] >= need && cums[k + 1] < need) {
                    int newneed = need - cums[k + 1];
                    ctl[g * 8]     = (int)((pf << 8) | (u32)(lane * 4 + k));
                    ctl[g * 8 + 1] = newneed;
                    if (newneed == hk[k] || ps == 0) { ctl[g * 8 + 3] = 1; ctl[g * 8 + 2] = 8 * ps; }
                }
            }
            int4 zz = {0, 0, 0, 0};
            *(int4*)(hist + g * 256 + lane * 4) = zz;
        }
        __syncthreads();
        if (ctl[3] && ctl[11] && ctl[19] && ctl[27]) break;
    }

    // ---- selection (wave-private; values reconstructed bitwise via unokey) ----
    {
        u32 theta = (u32)ctl[g * 8];
        int shift = ctl[g * 8 + 2];
        int need  = ctl[g * 8 + 1];
        int base  = K_ - need;
        int a2 = 0;
        for (int i = lane; i < NC_; i += 64) {
            u32 k = kreg[a2++];
            u32 hp = k >> shift;
            int slot = -1;
            if (hp > theta) slot = atomicAdd(&ctl[g * 8 + 4], 1);
            else if (hp == theta) {
                int j = atomicAdd(&ctl[g * 8 + 5], 1);
                if (j < need) slot = base + j;
            }
            if (slot >= 0) {
                int a = i / 21, b = i - a * 21;
                int ae = min(max(a, alo), ahi), be = min(max(b, blo), bhi);
                yiw[g * 100 + slot] = unokey(k);
                pab[g * 100 + slot] = ((ae + 4 * ri) << 8) | (be + 4 * ci);
            }
        }
    }
    // ---- softmax (wave-private) ----
    {
        float m = unokey(kmax);
        float wa = expf((yiw[g * 100 + lane] - m) * 10.f);
        float wb2 = (lane < 36) ? expf((yiw[g * 100 + 64 + lane] - m) * 10.f) : 0.f;
        float ssum = wa + wb2;
#pragma unroll
        for (int off = 1; off < 64; off <<= 1) ssum += __shfl_xor(ssum, off);
        float inv = 1.f / ssum;
        yiw[g * 100 + lane] = wa * inv;
        if (lane < 36) yiw[g * 100 + 64 + lane] = wb2 * inv;
    }

    // ---- PV: wave owns its query (R8 layout); channel-major atomics ----
    if (lane < 49) {
        int pi = lane / 7, pj = lane - pi * 7;
        int rsel = lane & 1;
        __half2 z[8];
#pragma unroll
        for (int j = 0; j < 8; j++) z[j] = __float2half2_rn(0.f);
        for (int k = 0; k < K_; k++) {
            float y = yiw[g * 100 + k];
            int pp = pab[g * 100 + k];
            int row = (pp >> 8) + pi, col = (pp & 255) + pj;
            const __half2* cell = Wp + (row * 32 + col) * 8;
            int4 A0 = *(const int4*)(cell + rsel * 4);
            int4 A1 = *(const int4*)(cell + 4 - rsel * 4);
            const __half2* pa = (const __half2*)&A0;
            const __half2* pb2 = (const __half2*)&A1;
            __half2 yh = __float2half2_rn(y);
#pragma unroll
            for (int j = 0; j < 4; j++) {
                z[j]     = __hfma2(pa[j],  yh, z[j]);
                z[4 + j] = __hfma2(pb2[j], yh, z[4 + j]);
            }
        }
        int orow = min(qiq + pi, 95), ocol = min(qjq + pj, 95);
        float* dst = ACCb + t * CI_ * HW_ + orow * 96 + ocol;
        int c0 = rsel * 8, c1 = 8 - c0;
#pragma unroll
        for (int jh = 0; jh < 4; jh++) {
            atomicAdd(dst + (c0 + 2 * jh) * HW_,     __low2float(z[jh]));
            atomicAdd(dst + (c0 + 2 * jh + 1) * HW_, __high2float(z[jh]));
            atomicAdd(dst + (c1 + 2 * jh) * HW_,     __low2float(z[4 + jh]));
            atomicAdd(dst + (c1 + 2 * jh + 1) * HW_, __high2float(z[4 + jh]));
        }
    }
}

// ---------------- final: y = ACC/Z (Z analytic), conv1x1 + residual ----------------
__global__ __launch_bounds__(256) void out_k(const void* vid, const void* Ww, const void* Wb,
                                             const float* __restrict__ ACCb, void* out)
{
    __shared__ float w[1088];
    __shared__ int sflag;
    int tid = threadIdx.x;
    int isbf = detect_flag(vid, tid, &sflag);
    if (isbf) { for (int i = tid; i < 1088; i += 256) w[i] = (i < 1024) ? ldbf(Ww, i) : ldbf(Wb, i - 1024); }
    else      { for (int i = tid; i < 1088; i += 256) w[i] = (i < 1024) ? ldf (Ww, i) : ldf (Wb, i - 1024); }
    __syncthreads();

    int lane5 = tid & 31, oct = tid >> 5;
    int g0 = blockIdx.x * 32 + lane5;           // 1152*32 = 36864 exactly
    int t = g0 / HW_, pix = g0 - t * HW_;
    int pi = pix / 96, pj = pix - pi * 96;
    float invz = 1.f / (float)(cntdim(pi) * cntdim(pj));

    float y[CI_];
    int ab = t * CI_ * HW_ + pix;
#pragma unroll
    for (int ci = 0; ci < CI_; ci++) y[ci] = ACCb[ab + ci * HW_] * invz;

    int vb = t * C_ * HW_ + pix;
#pragma unroll
    for (int co = oct * 8; co < oct * 8 + 8; co++) {
        float s = w[1024 + co];
#pragma unroll
        for (int ci = 0; ci < CI_; ci++) s += w[co * 16 + ci] * y[ci];
        int idx = vb + co * HW_;
        float vv = isbf ? ldbf(vid, idx) : ldf(vid, idx);
        float r = vv + s;
        if (isbf) ((bf16*)out)[idx] = __float2bfloat16(r);
        else      ((float*)out)[idx] = r;
    }
}

extern "C" void kernel_launch(void* const* d_in, const int* in_sizes, int n_in,
                              void* d_out, int out_size, void* d_ws, size_t ws_size,
                              hipStream_t stream)
{
    // ws byte layout: B1p @0, B2h @2359296, B3p @3538944, ACC @5898240
    char* ws = (char*)d_ws;
    u32*    B1p  = (u32*)ws;
    __half* B2h  = (__half*)(ws + 2359296);
    u32*    B3p  = (u32*)(ws + 3538944);
    float*  ACCb = (float*)(ws + 5898240);

    conv3_k<<<dim3(576), dim3(256), 0, stream>>>(d_in[0], d_in[1], d_in[2], d_in[3], d_in[4],
                                                 d_in[5], d_in[6], B1p, B2h, B3p, ACCb);
    attn_k<<<dim3(144, T_), dim3(256), 0, stream>>>(B1p, B2h, B3p, ACCb);
    out_k<<<dim3(1152), dim3(256), 0, stream>>>(d_in[0], d_in[7], d_in[8], ACCb, d_out);
}

// Round 13
// 172.763 us; speedup vs baseline: 1.2760x; 1.0528x over previous
//
#include <hip/hip_runtime.h>
#include <hip/hip_bf16.h>
#include <hip/hip_fp16.h>
#include <math.h>

typedef __hip_bfloat16 bf16;
typedef unsigned int u32;
typedef __attribute__((ext_vector_type(8))) short short8;
typedef __attribute__((ext_vector_type(4))) float float4v;

#define T_   4
#define C_   64
#define H_   96
#define W_   96
#define CI_  16
#define HW_  9216
#define NC_  441
#define K_   100
#define HSEL 0x07060302u
#define LSEL 0x05040100u

__device__ __forceinline__ float ldbf(const void* p, int i) { return __bfloat162float(((const bf16*)p)[i]); }
__device__ __forceinline__ float ldf (const void* p, int i) { return ((const float*)p)[i]; }

__device__ __forceinline__ unsigned short f2bf(float x) {
    union { float f; u32 u; } a; a.f = x;
    u32 r = a.u + 0x7FFF + ((a.u >> 16) & 1);
    return (unsigned short)(r >> 16);
}
__device__ __forceinline__ float bf2f(unsigned short s) {
    union { u32 u; float f; } a; a.u = ((u32)s) << 16;
    return a.f;
}
__device__ __forceinline__ u32 packbf(float x) {
    unsigned short h = f2bf(x);
    unsigned short l = f2bf(x - bf2f(h));
    return ((u32)h << 16) | (u32)l;
}
__device__ __forceinline__ u32 okey(float f) {
    u32 u = __float_as_uint(f);
    return u ^ ((u & 0x80000000u) ? 0xFFFFFFFFu : 0x80000000u);
}
__device__ __forceinline__ float unokey(u32 k) {
    u32 u = (k & 0x80000000u) ? (k ^ 0x80000000u) : ~k;
    return __uint_as_float(u);
}
__device__ __forceinline__ int cntdim(int x) {
    int c = 0;
#pragma unroll
    for (int pp = 0; pp < 7; pp++) {
        int q = x - pp;
        c += (q >= 0 && q <= 92 && ((q & 3) == 0)) ? 1 : 0;
    }
    if (x == 95) c += 3;
    return c;
}

// per-block dtype vote (fp32 low-mantissa words decode to "insane" bf16 exponents)
__device__ __forceinline__ int detect_flag(const void* vid, int tid, int* sflag) {
    if (tid < 64) {
        unsigned short w = ((const unsigned short*)vid)[tid * 2];
        int e = (w >> 7) & 0xFF;
        int sane = ((e >= 100 && e <= 140) || ((w & 0x7FFF) == 0)) ? 1 : 0;
#pragma unroll
        for (int off = 1; off < 64; off <<= 1) sane += __shfl_xor(sane, off);
        if (tid == 0) *sflag = (sane >= 48) ? 1 : 0;
    }
    __syncthreads();
    return *sflag;
}

// ---------------- conv1x1 x3 + format conversion + ACC zero (R6-proven) ----------------
__global__ __launch_bounds__(256) void conv3_k(const void* vid, const void* gw, const void* gb,
                                               const void* tw, const void* tb, const void* pw,
                                               const void* pb,
                                               u32* __restrict__ B1p, __half* __restrict__ B2h,
                                               u32* __restrict__ B3p, float* __restrict__ ACCb)
{
    __shared__ float w[3120];
    __shared__ int sflag;
    int tid = threadIdx.x;
    int isbf = detect_flag(vid, tid, &sflag);
    if (isbf) {
        for (int i = tid; i < 3120; i += 256) {
            float v;
            if (i < 1024) v = ldbf(gw, i);
            else if (i < 2048) v = ldbf(tw, i - 1024);
            else if (i < 3072) v = ldbf(pw, i - 2048);
            else if (i < 3088) v = ldbf(gb, i - 3072);
            else if (i < 3104) v = ldbf(tb, i - 3088);
            else v = ldbf(pb, i - 3104);
            w[i] = v;
        }
    } else {
        for (int i = tid; i < 3120; i += 256) {
            float v;
            if (i < 1024) v = ldf(gw, i);
            else if (i < 2048) v = ldf(tw, i - 1024);
            else if (i < 3072) v = ldf(pw, i - 2048);
            else if (i < 3088) v = ldf(gb, i - 3072);
            else if (i < 3104) v = ldf(tb, i - 3088);
            else v = ldf(pb, i - 3104);
            w[i] = v;
        }
    }
    __syncthreads();

    {
        float4v z = {0.f, 0.f, 0.f, 0.f};
        *(float4v*)(ACCb + (blockIdx.x * 256 + tid) * 4) = z;
    }

    int lane = tid & 63, og = tid >> 6;
    int g0 = blockIdx.x * 64 + lane;          // 576*64 = 36864 exactly
    int t = g0 / HW_, pix = g0 - t * HW_;

    float a1[4], a2[4], a3[4];
#pragma unroll
    for (int k = 0; k < 4; k++) {
        a1[k] = w[3072 + og * 4 + k];
        a2[k] = w[3088 + og * 4 + k];
        a3[k] = w[3104 + og * 4 + k];
    }
    int base = t * C_ * HW_ + pix;
#pragma unroll 16
    for (int c = 0; c < C_; c++) {
        float v = isbf ? ldbf(vid, base + c * HW_) : ldf(vid, base + c * HW_);
#pragma unroll
        for (int k = 0; k < 4; k++) {
            a1[k] += v * w[(og * 4 + k) * 64 + c];
            a2[k] += v * w[1024 + (og * 4 + k) * 64 + c];
            a3[k] += v * w[2048 + (og * 4 + k) * 64 + c];
        }
    }
    int ob = g0 * 16 + og * 4;
    uint4 p1, p3;
    p1.x = packbf(a1[0]); p1.y = packbf(a1[1]); p1.z = packbf(a1[2]); p1.w = packbf(a1[3]);
    p3.x = packbf(a3[0]); p3.y = packbf(a3[1]); p3.z = packbf(a3[2]); p3.w = packbf(a3[3]);
    *(uint4*)(B1p + ob) = p1;
    *(uint4*)(B3p + ob) = p3;
    __half2 h01 = __floats2half2_rn(a2[0], a2[1]);
    __half2 h23 = __floats2half2_rn(a2[2], a2[3]);
    uint2 p2;
    p2.x = *(u32*)&h01; p2.y = *(u32*)&h23;
    *(uint2*)(B2h + ob) = p2;
}

// ---------------- fused attention: one block = 2x2 queries, 512 threads (8 waves) ----------------
// Same math as R12 (bit-identical). Thread-parallel phases halve; top-k/softmax stay
// wave-private on waves 0-3; PV splits k-halves across wave pairs with Zc combine.
__global__ __launch_bounds__(512, 6) void attn_k(const u32* __restrict__ B1p,
                                                 const __half* __restrict__ B2h,
                                                 const u32* __restrict__ B3p,
                                                 float* __restrict__ ACCb)
{
    __shared__ __align__(16) char SM[51344];
    short*   Win  = (short*)SM;                  // [32][32][16] bf16 plane; PV f16 overlay
    float*   Sc   = (float*)(SM + 32768);        // [4][441]; Zc overlay after selection
    float*   Cb   = (float*)(SM + 39824);        // [8][256] score bounce
    int*     hist = (int*)(SM + 39824);          // topk overlay [4][256]
    float*   yiw  = (float*)(SM + 48016);        // [4][100]
    int*     pab  = (int*)(SM + 49616);          // [4][100]
    int*     ctl  = (int*)(SM + 51216);          // [4][8]
    __half2* Zc   = (__half2*)(SM + 32768);      // [4][49][8] PV combine (over Sc)
    __half2* Wp   = (__half2*)SM;                // PV plane [31][32][8] h2

    int tid = threadIdx.x;
    int tile = blockIdx.x, t = blockIdx.y;
    int qy = tile / 12, qx = tile - qy * 12;
    int qi = qy * 8, qj = qx * 8;

    const u32*    B1t = B1p + t * HW_ * 16;
    const __half* B2t = B2h + t * HW_ * 16;
    const u32*    B3t = B3p + t * HW_ * 16;

    int lane = tid & 63, wv = tid >> 6;          // wv in 0..7
    int nn = lane & 15, qsel = nn >> 3, pjn = nn & 7;
    int koff = (lane >> 4) * 8;

    // ---- stage h-plane: 32x32 window ----
    for (int pos = tid; pos < 1024; pos += 512) {
        int row = pos >> 5, col = pos & 31;
        int vr = min(max(qi - 10 + row, 0), 95);
        int vc = min(max(qj - 10 + col, 0), 95);
        const u32* src = B3t + (vr * 96 + vc) * 16;
        uint4 U0 = *(const uint4*)src,       U1 = *(const uint4*)(src + 4);
        uint4 U2 = *(const uint4*)(src + 8), U3 = *(const uint4*)(src + 12);
        uint4 A, B;
        A.x = __builtin_amdgcn_perm(U0.y, U0.x, HSEL);
        A.y = __builtin_amdgcn_perm(U0.w, U0.z, HSEL);
        A.z = __builtin_amdgcn_perm(U1.y, U1.x, HSEL);
        A.w = __builtin_amdgcn_perm(U1.w, U1.z, HSEL);
        B.x = __builtin_amdgcn_perm(U2.y, U2.x, HSEL);
        B.y = __builtin_amdgcn_perm(U2.w, U2.z, HSEL);
        B.z = __builtin_amdgcn_perm(U3.y, U3.x, HSEL);
        B.w = __builtin_amdgcn_perm(U3.w, U3.z, HSEL);
        *(uint4*)(Win + pos * 16)     = A;
        *(uint4*)(Win + pos * 16 + 8) = B;
    }
    __syncthreads();

    // ---- score phase A: Ah*Bh + Ah*Bl, query rows ri = 0,1; r strides 8 waves ----
#pragma unroll 1
    for (int ri = 0; ri < 2; ri++) {
        short8 Bh[4], Bl[4];
        int qiq = qi + 4 * ri, qjq = qj + 4 * qsel;
#pragma unroll
        for (int s = 0; s < 4; s++) {
            int kk0 = s * 32 + koff;
            int pi = kk0 >> 4, c0 = kk0 & 15;
            uint4 U0 = {0, 0, 0, 0}, U1 = {0, 0, 0, 0};
            if (pjn < 7 && pi < 7) {
                const u32* src = B1t + (min(qiq + pi, 95) * 96 + min(qjq + pjn, 95)) * 16 + c0;
                U0 = *(const uint4*)src;
                U1 = *(const uint4*)(src + 4);
            }
            union { uint4 u; short8 s8; } hc, lc;
            hc.u.x = __builtin_amdgcn_perm(U0.y, U0.x, HSEL);
            hc.u.y = __builtin_amdgcn_perm(U0.w, U0.z, HSEL);
            hc.u.z = __builtin_amdgcn_perm(U1.y, U1.x, HSEL);
            hc.u.w = __builtin_amdgcn_perm(U1.w, U1.z, HSEL);
            lc.u.x = __builtin_amdgcn_perm(U0.y, U0.x, LSEL);
            lc.u.y = __builtin_amdgcn_perm(U0.w, U0.z, LSEL);
            lc.u.z = __builtin_amdgcn_perm(U1.y, U1.x, LSEL);
            lc.u.w = __builtin_amdgcn_perm(U1.w, U1.z, LSEL);
            Bh[s] = hc.s8; Bl[s] = lc.s8;
        }
        float* Cw = Cb + wv * 256;
        for (int r = wv; r < 21; r += 8) {
            float psum = 0.f;
            int v = (lane >= 21) ? 1 : 0;
            int b = lane - v * 21;
#pragma unroll
            for (int st = 0; st < 2; st++) {
                float4v acc = {0.f, 0.f, 0.f, 0.f};
#pragma unroll
                for (int s = 0; s < 4; s++) {
                    int arow = 4 * ri + r + 2 * s + (lane >> 5);
                    int aoff = (arow * 32 + st * 16 + nn) * 16 + ((lane >> 4) & 1) * 8;
                    short8 A = *(const short8*)(Win + aoff);
                    acc = __builtin_amdgcn_mfma_f32_16x16x32_bf16(A, Bh[s], acc, 0, 0, 0);
                    acc = __builtin_amdgcn_mfma_f32_16x16x32_bf16(A, Bl[s], acc, 0, 0, 0);
                }
                *(float4v*)(Cw + nn * 16 + (lane >> 4) * 4) = acc;
                if (lane < 42) {
#pragma unroll
                    for (int pj = 0; pj < 7; pj++) {
                        int sp = b + 4 * v + pj;
                        if ((sp >> 4) == st) psum += Cw[(8 * v + pj) * 16 + (sp & 15)];
                    }
                }
            }
            if (lane < 42) Sc[(ri * 2 + v) * 441 + r * 21 + b] = psum;
        }
    }
    __syncthreads();

    // ---- stage l-plane (same packed source, L1-hot) ----
    for (int pos = tid; pos < 1024; pos += 512) {
        int row = pos >> 5, col = pos & 31;
        int vr = min(max(qi - 10 + row, 0), 95);
        int vc = min(max(qj - 10 + col, 0), 95);
        const u32* src = B3t + (vr * 96 + vc) * 16;
        uint4 U0 = *(const uint4*)src,       U1 = *(const uint4*)(src + 4);
        uint4 U2 = *(const uint4*)(src + 8), U3 = *(const uint4*)(src + 12);
        uint4 A, B;
        A.x = __builtin_amdgcn_perm(U0.y, U0.x, LSEL);
        A.y = __builtin_amdgcn_perm(U0.w, U0.z, LSEL);
        A.z = __builtin_amdgcn_perm(U1.y, U1.x, LSEL);
        A.w = __builtin_amdgcn_perm(U1.w, U1.z, LSEL);
        B.x = __builtin_amdgcn_perm(U2.y, U2.x, LSEL);
        B.y = __builtin_amdgcn_perm(U2.w, U2.z, LSEL);
        B.z = __builtin_amdgcn_perm(U3.y, U3.x, LSEL);
        B.w = __builtin_amdgcn_perm(U3.w, U3.z, LSEL);
        *(uint4*)(Win + pos * 16)     = A;
        *(uint4*)(Win + pos * 16 + 8) = B;
    }
    __syncthreads();

    // ---- score phase B: Sc += Al*Bh ----
#pragma unroll 1
    for (int ri = 0; ri < 2; ri++) {
        short8 Bh[4];
        int qiq = qi + 4 * ri, qjq = qj + 4 * qsel;
#pragma unroll
        for (int s = 0; s < 4; s++) {
            int kk0 = s * 32 + koff;
            int pi = kk0 >> 4, c0 = kk0 & 15;
            uint4 U0 = {0, 0, 0, 0}, U1 = {0, 0, 0, 0};
            if (pjn < 7 && pi < 7) {
                const u32* src = B1t + (min(qiq + pi, 95) * 96 + min(qjq + pjn, 95)) * 16 + c0;
                U0 = *(const uint4*)src;
                U1 = *(const uint4*)(src + 4);
            }
            union { uint4 u; short8 s8; } hc;
            hc.u.x = __builtin_amdgcn_perm(U0.y, U0.x, HSEL);
            hc.u.y = __builtin_amdgcn_perm(U0.w, U0.z, HSEL);
            hc.u.z = __builtin_amdgcn_perm(U1.y, U1.x, HSEL);
            hc.u.w = __builtin_amdgcn_perm(U1.w, U1.z, HSEL);
            Bh[s] = hc.s8;
        }
        float* Cw = Cb + wv * 256;
        for (int r = wv; r < 21; r += 8) {
            float psum = 0.f;
            int v = (lane >= 21) ? 1 : 0;
            int b = lane - v * 21;
#pragma unroll
            for (int st = 0; st < 2; st++) {
                float4v acc = {0.f, 0.f, 0.f, 0.f};
#pragma unroll
                for (int s = 0; s < 4; s++) {
                    int arow = 4 * ri + r + 2 * s + (lane >> 5);
                    int aoff = (arow * 32 + st * 16 + nn) * 16 + ((lane >> 4) & 1) * 8;
                    short8 A = *(const short8*)(Win + aoff);
                    acc = __builtin_amdgcn_mfma_f32_16x16x32_bf16(A, Bh[s], acc, 0, 0, 0);
                }
                *(float4v*)(Cw + nn * 16 + (lane >> 4) * 4) = acc;
                if (lane < 42) {
#pragma unroll
                    for (int pj = 0; pj < 7; pj++) {
                        int sp = b + 4 * v + pj;
                        if ((sp >> 4) == st) psum += Cw[(8 * v + pj) * 16 + (sp & 15)];
                    }
                }
            }
            if (lane < 42) Sc[(ri * 2 + v) * 441 + r * 21 + b] += psum;
        }
    }
    __syncthreads();

    // ---- stage PV f16 plane + init hist/ctl ----
    for (int pos = tid; pos < 992; pos += 512) {
        int row = pos >> 5, col = pos & 31;
        int vr = min(max(qi - 10 + row, 0), 95);
        int vc = min(max(qj - 10 + col, 0), 95);
        const __half* src = B2t + (vr * 96 + vc) * 16;
        *(int4*)(Wp + pos * 8)     = *(const int4*)src;
        *(int4*)(Wp + pos * 8 + 4) = *(const int4*)(src + 8);
    }
    hist[tid] = 0; hist[512 + tid] = 0;
    if (tid < 32) ctl[tid] = ((tid & 7) == 1) ? K_ : 0;
    __syncthreads();

    // ---- adaptive radix-256 exact top-100: waves 0-3 own queries; clip-remapped keys ----
    int g = wv & 3;
    int ri = g >> 1, ci = g & 1;
    int qiq = qi + 4 * ri, qjq = qj + 4 * ci;
    int alo = max(0, 10 - qiq), ahi = min(20, 105 - qiq);
    int blo = max(0, 10 - qjq), bhi = min(20, 105 - qjq);
    u32 kreg[7]; int ni = 0;
    u32 kmax = 0;
    if (wv < 4) {
        for (int i = lane; i < NC_; i += 64) {
            int aa = i / 21, bb = i - aa * 21;
            int ae = min(max(aa, alo), ahi), be = min(max(bb, blo), bhi);
            u32 k = okey(Sc[g * 441 + ae * 21 + be]);
            kmax = max(kmax, k);
            kreg[ni++] = k;
        }
#pragma unroll
        for (int off = 1; off < 64; off <<= 1) kmax = max(kmax, (u32)__shfl_xor((int)kmax, off));
    }

    for (int ps = 3; ps >= 0; ps--) {
        if (wv < 4 && !ctl[g * 8 + 3]) {
            u32 pref = (u32)ctl[g * 8];
            for (int a = 0; a < ni; a++) {
                u32 k = kreg[a];
                if (ps == 3 || (k >> ((ps + 1) * 8)) == pref)
                    atomicAdd(&hist[g * 256 + ((k >> (ps * 8)) & 255)], 1);
            }
        }
        __syncthreads();
        if (wv < 4 && !ctl[g * 8 + 3]) {
            int4 hv = *(int4*)(hist + g * 256 + lane * 4);
            int local = hv.x + hv.y + hv.z + hv.w;
            int s = local;
#pragma unroll
            for (int off = 1; off < 64; off <<= 1) {
                int tt = __shfl_down(s, off);
                if (lane + off < 64) s += tt;
            }
            int c4 = s - local;
            int c3 = c4 + hv.w, c2 = c3 + hv.z, c1 = c2 + hv.y, c0 = s;
            int need = ctl[g * 8 + 1];
            u32 pf = (u32)ctl[g * 8];
            int cums[5] = {c0, c1, c2, c3, c4};
            int hk[4] = {hv.x, hv.y, hv.z, hv.w};
#pragma unroll
            for (int k = 0; k < 4; k++) {
                if (cums[k] >= need && cums[k + 1] < need) {
                    int newneed = need - cums[k + 1];
                    ctl[g * 8]     = (int)((pf << 8) | (u32)(lane * 4 + k));
                    ctl[g * 8 + 1] = newneed;
                    if (newneed == hk[k] || ps == 0) { ctl[g * 8 + 3] = 1; ctl[g * 8 + 2] = 8 * ps; }
                }
            }
            int4 zz = {0, 0, 0, 0};
            *(int4*)(hist + g * 256 + lane * 4) = zz;
        }
        __syncthreads();
        if (ctl[3] && ctl[11] && ctl[19] && ctl[27]) break;
    }

    // ---- selection + softmax (wave-private, waves 0-3) ----
    if (wv < 4) {
        u32 theta = (u32)ctl[g * 8];
        int shift = ctl[g * 8 + 2];
        int need  = ctl[g * 8 + 1];
        int base  = K_ - need;
        int a2 = 0;
        for (int i = lane; i < NC_; i += 64) {
            u32 k = kreg[a2++];
            u32 hp = k >> shift;
            int slot = -1;
            if (hp > theta) slot = atomicAdd(&ctl[g * 8 + 4], 1);
            else if (hp == theta) {
                int j = atomicAdd(&ctl[g * 8 + 5], 1);
                if (j < need) slot = base + j;
            }
            if (slot >= 0) {
                int a = i / 21, b = i - a * 21;
                int ae = min(max(a, alo), ahi), be = min(max(b, blo), bhi);
                yiw[g * 100 + slot] = unokey(k);
                pab[g * 100 + slot] = ((ae + 4 * ri) << 8) | (be + 4 * ci);
            }
        }
        float m = unokey(kmax);
        float wa = expf((yiw[g * 100 + lane] - m) * 10.f);
        float wb2 = (lane < 36) ? expf((yiw[g * 100 + 64 + lane] - m) * 10.f) : 0.f;
        float ssum = wa + wb2;
#pragma unroll
        for (int off = 1; off < 64; off <<= 1) ssum += __shfl_xor(ssum, off);
        float inv = 1.f / ssum;
        yiw[g * 100 + lane] = wa * inv;
        if (lane < 36) yiw[g * 100 + 64 + lane] = wb2 * inv;
    }
    __syncthreads();

    // ---- PV: wave pair per query (kh = wv>>2 halves of k); Zc combine; channel-major atomics ----
    {
        int kh = wv >> 2;
        __half2 z[8];
        int rsel = lane & 1;
        int pi = lane / 7, pj = lane - pi * 7;
        if (lane < 49) {
#pragma unroll
            for (int j = 0; j < 8; j++) z[j] = __float2half2_rn(0.f);
            int kb2 = kh * 50;
            for (int k = kb2; k < kb2 + 50; k++) {
                float y = yiw[g * 100 + k];
                int pp = pab[g * 100 + k];
                int row = (pp >> 8) + pi, col = (pp & 255) + pj;
                const __half2* cell = Wp + (row * 32 + col) * 8;
                int4 A0 = *(const int4*)(cell + rsel * 4);
                int4 A1 = *(const int4*)(cell + 4 - rsel * 4);
                const __half2* pa = (const __half2*)&A0;
                const __half2* pb2 = (const __half2*)&A1;
                __half2 yh = __float2half2_rn(y);
#pragma unroll
                for (int j = 0; j < 4; j++) {
                    z[j]     = __hfma2(pa[j],  yh, z[j]);
                    z[4 + j] = __hfma2(pb2[j], yh, z[4 + j]);
                }
            }
        }
        if (kh == 1 && lane < 49) {
            *(int4*)(Zc + (g * 49 + lane) * 8)     = *(int4*)(z);
            *(int4*)(Zc + (g * 49 + lane) * 8 + 4) = *(int4*)(z + 4);
        }
        __syncthreads();
        if (kh == 0 && lane < 49) {
            const __half2* zo = Zc + (g * 49 + lane) * 8;
#pragma unroll
            for (int j = 0; j < 8; j++) z[j] = __hadd2(z[j], zo[j]);
            int orow = min(qiq + pi, 95), ocol = min(qjq + pj, 95);
            float* dst = ACCb + t * CI_ * HW_ + orow * 96 + ocol;
            int c0 = rsel * 8, c1 = 8 - c0;
#pragma unroll
            for (int jh = 0; jh < 4; jh++) {
                atomicAdd(dst + (c0 + 2 * jh) * HW_,     __low2float(z[jh]));
                atomicAdd(dst + (c0 + 2 * jh + 1) * HW_, __high2float(z[jh]));
                atomicAdd(dst + (c1 + 2 * jh) * HW_,     __low2float(z[4 + jh]));
                atomicAdd(dst + (c1 + 2 * jh + 1) * HW_, __high2float(z[4 + jh]));
            }
        }
    }
}

// ---------------- final: y = ACC/Z (Z analytic), conv1x1 + residual ----------------
__global__ __launch_bounds__(256) void out_k(const void* vid, const void* Ww, const void* Wb,
                                             const float* __restrict__ ACCb, void* out)
{
    __shared__ float w[1088];
    __shared__ int sflag;
    int tid = threadIdx.x;
    int isbf = detect_flag(vid, tid, &sflag);
    if (isbf) { for (int i = tid; i < 1088; i += 256) w[i] = (i < 1024) ? ldbf(Ww, i) : ldbf(Wb, i - 1024); }
    else      { for (int i = tid; i < 1088; i += 256) w[i] = (i < 1024) ? ldf (Ww, i) : ldf (Wb, i - 1024); }
    __syncthreads();

    int lane5 = tid & 31, oct = tid >> 5;
    int g0 = blockIdx.x * 32 + lane5;           // 1152*32 = 36864 exactly
    int t = g0 / HW_, pix = g0 - t * HW_;
    int pi = pix / 96, pj = pix - pi * 96;
    float invz = 1.f / (float)(cntdim(pi) * cntdim(pj));

    float y[CI_];
    int ab = t * CI_ * HW_ + pix;
#pragma unroll
    for (int ci = 0; ci < CI_; ci++) y[ci] = ACCb[ab + ci * HW_] * invz;

    int vb = t * C_ * HW_ + pix;
#pragma unroll
    for (int co = oct * 8; co < oct * 8 + 8; co++) {
        float s = w[1024 + co];
#pragma unroll
        for (int ci = 0; ci < CI_; ci++) s += w[co * 16 + ci] * y[ci];
        int idx = vb + co * HW_;
        float vv = isbf ? ldbf(vid, idx) : ldf(vid, idx);
        float r = vv + s;
        if (isbf) ((bf16*)out)[idx] = __float2bfloat16(r);
        else      ((float*)out)[idx] = r;
    }
}

extern "C" void kernel_launch(void* const* d_in, const int* in_sizes, int n_in,
                              void* d_out, int out_size, void* d_ws, size_t ws_size,
                              hipStream_t stream)
{
    // ws byte layout: B1p @0, B2h @2359296, B3p @3538944, ACC @5898240
    char* ws = (char*)d_ws;
    u32*    B1p  = (u32*)ws;
    __half* B2h  = (__half*)(ws + 2359296);
    u32*    B3p  = (u32*)(ws + 3538944);
    float*  ACCb = (float*)(ws + 5898240);

    conv3_k<<<dim3(576), dim3(256), 0, stream>>>(d_in[0], d_in[1], d_in[2], d_in[3], d_in[4],
                                                 d_in[5], d_in[6], B1p, B2h, B3p, ACCb);
    attn_k<<<dim3(144, T_), dim3(512), 0, stream>>>(B1p, B2h, B3p, ACCb);
    out_k<<<dim3(1152), dim3(256), 0, stream>>>(d_in[0], d_in[7], d_in[8], ACCb, d_out);
}